// Round 24
// baseline (1560.336 us; speedup 1.0000x reference)
//
#include <hip/hip_runtime.h>
#include <math.h>

namespace {

constexpr int NB   = 4;
constexpr int SEQ  = 512;
constexpr int HS_  = 512;
constexpr int NH_  = 8;
constexpr int NL_  = 6;
constexpr int FF_  = 2048;
constexpr int VOC_ = 32000;
constexpr int MT   = NB * SEQ;   // 2048 token rows

typedef __attribute__((ext_vector_type(8))) short short8;   // 8 bf16 = 4 VGPRs
typedef __attribute__((ext_vector_type(4))) float f32x4;    // MFMA accumulator
typedef unsigned short u16;

__device__ inline float b2f(u16 u) {
    unsigned i = ((unsigned)u) << 16; float f; __builtin_memcpy(&f, &i, 4); return f;
}
__device__ inline u16 f2b(float f) {
    unsigned i; __builtin_memcpy(&i, &f, 4);
    i += 0x7fffu + ((i >> 16) & 1u);            // round-nearest-even
    return (u16)(i >> 16);
}

template<int N> __device__ __forceinline__ void vm_wait() {
    asm volatile("s_waitcnt vmcnt(%0)" :: "n"(N) : "memory");
}

// ---------------- embedding + sinusoidal PE: enc rows [0,MT), dec rows [MT,2MT) ----------------
__global__ __launch_bounds__(256)
void k_embed2(const int* __restrict__ xtok, const float* __restrict__ eemb, float* __restrict__ zo,
              const int* __restrict__ ytok, const float* __restrict__ demb, float* __restrict__ ho)
{
    int row = blockIdx.x;
    const int* tok; const float* emb; float* out;
    if (row < MT) { tok = xtok; emb = eemb; out = zo; }
    else          { row -= MT; tok = ytok; emb = demb; out = ho; }
    int s = row & (SEQ - 1);
    int t = tok[row];
    const float* e = emb + (size_t)t * HS_;
    float* o = out + (size_t)row * HS_;
    for (int i = threadIdx.x; i < HS_; i += 256) {
        int half = i >> 1;
        float freq = powf(10000.0f, -(float)half / (float)HS_);
        float ang = (float)s * freq;
        float pe = (i & 1) ? cosf(ang) : sinf(ang);
        o[i] = e[i] + pe;
    }
}

// ---------------- layernorm row body: one WAVE per row of 512, bf16 out ----------------
__device__ inline void ln_row(int lane, const float* __restrict__ x, const float* __restrict__ g,
                              const float* __restrict__ b, u16* __restrict__ o)
{
    const float* xp = x + lane * 8;
    float4 u0 = *(const float4*)xp;
    float4 u1 = *(const float4*)(xp + 4);
    float v[8] = {u0.x, u0.y, u0.z, u0.w, u1.x, u1.y, u1.z, u1.w};
    float s = 0.f, s2 = 0.f;
    #pragma unroll
    for (int i = 0; i < 8; i++) { s += v[i]; s2 += v[i] * v[i]; }
    #pragma unroll
    for (int off = 32; off; off >>= 1) { s += __shfl_xor(s, off); s2 += __shfl_xor(s2, off); }
    float mean = s * (1.0f / HS_);
    float var  = s2 * (1.0f / HS_) - mean * mean;
    float rstd = rsqrtf(var + 1e-5f);
    const float* gp = g + lane * 8;
    const float* bp = b + lane * 8;
    float4 g0 = *(const float4*)gp, g1 = *(const float4*)(gp + 4);
    float4 b0 = *(const float4*)bp, b1 = *(const float4*)(bp + 4);
    float gv[8] = {g0.x, g0.y, g0.z, g0.w, g1.x, g1.y, g1.z, g1.w};
    float bv[8] = {b0.x, b0.y, b0.z, b0.w, b1.x, b1.y, b1.z, b1.w};
    unsigned w[4];
    #pragma unroll
    for (int j = 0; j < 4; j++) {
        u16 lo = f2b((v[2*j]   - mean) * rstd * gv[2*j]   + bv[2*j]);
        u16 hi = f2b((v[2*j+1] - mean) * rstd * gv[2*j+1] + bv[2*j+1]);
        w[j] = (unsigned)lo | ((unsigned)hi << 16);
    }
    int4 ov; ov.x = w[0]; ov.y = w[1]; ov.z = w[2]; ov.w = w[3];
    *(int4*)(o + lane * 8) = ov;
}

// 256 threads = 4 waves, 4 rows per block (grid MT/4)
__global__ __launch_bounds__(256)
void k_ln(const float* __restrict__ in, const float* __restrict__ g,
          const float* __restrict__ b, u16* __restrict__ out)
{
    int row = (blockIdx.x << 2) + (threadIdx.x >> 6);
    ln_row(threadIdx.x & 63, in + (size_t)row * HS_, g, b, out + (size_t)row * HS_);
}

// two LN streams (same gamma/beta) in one launch; grid 2*MT/4
__global__ __launch_bounds__(256)
void k_ln2(const float* __restrict__ in1, u16* __restrict__ out1,
           const float* __restrict__ in2, u16* __restrict__ out2,
           const float* __restrict__ g, const float* __restrict__ b)
{
    int row = (blockIdx.x << 2) + (threadIdx.x >> 6);
    int lane = threadIdx.x & 63;
    if (row < MT) ln_row(lane, in1 + (size_t)row * HS_, g, b, out1 + (size_t)row * HS_);
    else {
        row -= MT;
        ln_row(lane, in2 + (size_t)row * HS_, g, b, out2 + (size_t)row * HS_);
    }
}

// ---------------- weight transpose+convert: W[K][N] fp32 -> Wt[N][K] bf16 ----------------
__global__ __launch_bounds__(256)
void k_wt(const float* __restrict__ s0, u16* __restrict__ dst, int K, int N)
{
    __shared__ float L[32][33];
    int k0 = blockIdx.x << 5, n0 = blockIdx.y << 5;
    int t = threadIdx.x;
    int r = t >> 3, c4 = (t & 7) << 2;
    float4 v = *(const float4*)(s0 + (size_t)(k0 + r) * N + n0 + c4);
    L[r][c4 + 0] = v.x; L[r][c4 + 1] = v.y; L[r][c4 + 2] = v.z; L[r][c4 + 3] = v.w;
    __syncthreads();
    int n = t >> 3, kq = (t & 7) << 2;
    ushort4 o;
    o.x = f2b(L[kq + 0][n]);
    o.y = f2b(L[kq + 1][n]);
    o.z = f2b(L[kq + 2][n]);
    o.w = f2b(L[kq + 3][n]);
    *(ushort4*)&dst[(size_t)(n0 + n) * K + k0 + kq] = o;
}

// ---------------- batched weight convert: many mats in one launch ----------------
struct WSlots {
    const float* src[10];
    unsigned long long dof[10];  // dst offset in shorts
    int tstart[10];
    int ktiles[10];
    int K[10];
    int N[10];
    int ns;
};

__global__ __launch_bounds__(256)
void k_wtm(WSlots s, u16* __restrict__ base)
{
    __shared__ float L[32][33];
    int bx = blockIdx.x;
    int j = 0;
    for (int t = 1; t < s.ns; t++) if (bx >= s.tstart[t]) j = t;
    int local = bx - s.tstart[j];
    int kt = s.ktiles[j];
    int k0 = (local % kt) << 5;
    int n0 = (local / kt) << 5;
    const float* src = s.src[j];
    int K = s.K[j], N = s.N[j];
    u16* dst = base + s.dof[j];

    int t = threadIdx.x;
    int r = t >> 3, c4 = (t & 7) << 2;
    float4 v = *(const float4*)(src + (size_t)(k0 + r) * N + n0 + c4);
    L[r][c4 + 0] = v.x; L[r][c4 + 1] = v.y; L[r][c4 + 2] = v.z; L[r][c4 + 3] = v.w;
    __syncthreads();
    int n = t >> 3, kq = (t & 7) << 2;
    ushort4 o;
    o.x = f2b(L[kq + 0][n]);
    o.y = f2b(L[kq + 1][n]);
    o.z = f2b(L[kq + 2][n]);
    o.w = f2b(L[kq + 3][n]);
    *(ushort4*)&dst[(size_t)(n0 + n) * K + k0 + kq] = o;
}

// ---------------- bf16 MFMA GEMM: C[M][N] = A[M][K] @ Wt[N][K]^T ----------------
// Per-dispatch configs (measured; TLP/blocks-per-CU is the dominant lever):
//  N=512 GEMMs: 32x32 (4/CU, r17). QKV/CKV: 32x64 (6/4 per CU, r16).
//  FFN1: 64x64 (4/CU, r18). Vocab: 64x128 BK=32 DB=1 (50% occ, r23)
//   + XCD swizzle + fused LSE partials; bf16 logits out when ws permits.
// Per-layer wconv kept (r21 lesson: just-in-time conversion keeps weights L2-warm).
// Rule #21: swizzle on per-lane GLOBAL source, LDS written linearly.
template<int BM, int BN, int BK, int DB, int RELU, int OUTBF, int LSE, int SWZ>
__global__ __launch_bounds__(256)
void k_mm(const u16* __restrict__ A, const u16* __restrict__ Wt,
          const float* __restrict__ bias, const float* resid,
          void* Cout, int M, int N, int K, int ldc,
          float* __restrict__ pmax, float* __restrict__ psum)
{
    constexpr int MR = BM / 32;      // frag rows per wave
    constexpr int NR = BN / 32;      // frag cols per wave
    constexpr int RPL = (BK == 64) ? 8 : 16;        // rows per gload_lds (1KB)
    constexpr int AIW = BM / (4 * RPL) ? BM / (4 * RPL) : 1;  // gloads per wave (A)
    constexpr int BIW = BN / (4 * RPL) ? BN / (4 * RPL) : 1;
    constexpr int NLD = AIW + BIW;
    constexpr int RS  = BK;                          // row stride in shorts
    __shared__ __align__(16) u16 As[(DB ? 2 : 1) * BM * BK];
    __shared__ __align__(16) u16 Bs[(DB ? 2 : 1) * BN * BK];
    __shared__ float Rm[LSE ? BM * 2 : 1];
    __shared__ float Rs[LSE ? BM * 2 : 1];

    const int tid  = threadIdx.x;
    const int lane = tid & 63;
    const int w    = tid >> 6;

    int bm, bn, bnIdx;
    if (SWZ) {
        int q = gridDim.x >> 3;
        int logical = (blockIdx.x & 7) * q + (blockIdx.x >> 3);
        int mtiles = M / BM;
        bnIdx = logical / mtiles;
        bm = (logical % mtiles) * BM;
        bn = bnIdx * BN;
    } else {
        bn = blockIdx.x * BN; bm = blockIdx.y * BM; bnIdx = blockIdx.x;
    }
    const int wm = (w >> 1) * (MR * 16), wn = (w & 1) * (NR * 16);
    const int fr = lane & 15, fs = lane >> 4;

    // staging geometry (per-lane global pre-swizzle, wave-uniform LDS base)
    const int lrow = lane / (BK / 8);                // BK=64: lane>>3, BK=32: lane>>2
    const int lchk = lane & (BK / 8 - 1);            // chunk within row
    constexpr int SWM = BK / 8 - 1;                  // swizzle mask: 7 or 3
    const u16* aSrc[4]; const u16* bSrc[4];
    int aOff[4], bOff[4];
    #pragma unroll
    for (int j = 0; j < AIW; j++) {
        int row = w * (BM / 4) + j * RPL + lrow;
        aSrc[j] = A + (size_t)(bm + row) * K + ((lchk ^ (row & SWM)) << 3);
        aOff[j] = (w * (BM / 4) + j * RPL) * RS;
    }
    #pragma unroll
    for (int j = 0; j < BIW; j++) {
        int row = w * (BN / 4) + j * RPL + lrow;
        bSrc[j] = Wt + (size_t)(bn + row) * K + ((lchk ^ (row & SWM)) << 3);
        bOff[j] = (w * (BN / 4) + j * RPL) * RS;
    }

    f32x4 acc[MR][NR];
    #pragma unroll
    for (int i = 0; i < MR; i++)
        #pragma unroll
        for (int j = 0; j < NR; j++)
            acc[i][j] = (f32x4){0.f, 0.f, 0.f, 0.f};

    auto compute_tile = [&](const u16* Ab, const u16* Bb) {
        #pragma unroll
        for (int kk = 0; kk < BK / 32; kk++) {
            short8 av[MR], bv[NR];
            #pragma unroll
            for (int i = 0; i < MR; i++) {
                int r = wm + (i << 4) + fr;
                int slot = (((kk << 2) | fs) ^ (r & SWM));
                av[i] = *(const short8*)&Ab[r * RS + (slot << 3)];
            }
            #pragma unroll
            for (int i = 0; i < NR; i++) {
                int r = wn + (i << 4) + fr;
                int slot = (((kk << 2) | fs) ^ (r & SWM));
                bv[i] = *(const short8*)&Bb[r * RS + (slot << 3)];
            }
            #pragma unroll
            for (int mi = 0; mi < MR; mi++)
                #pragma unroll
                for (int ni = 0; ni < NR; ni++)
                    acc[mi][ni] = __builtin_amdgcn_mfma_f32_16x16x32_bf16(
                        av[mi], bv[ni], acc[mi][ni], 0, 0, 0);
        }
    };

    if (DB) {
        // double-buffer, prefetch, counted vmcnt, raw barriers
        #pragma unroll
        for (int j = 0; j < AIW; j++)
            __builtin_amdgcn_global_load_lds((const u16*)aSrc[j], (u16*)&As[aOff[j]], 16, 0, 0);
        #pragma unroll
        for (int j = 0; j < BIW; j++)
            __builtin_amdgcn_global_load_lds((const u16*)bSrc[j], (u16*)&Bs[bOff[j]], 16, 0, 0);
        const int nt = K / BK;
        for (int t = 0; t < nt; t++) {
            const int cur = t & 1;
            if (t + 1 < nt) {
                const int k1 = (t + 1) * BK;
                #pragma unroll
                for (int j = 0; j < AIW; j++)
                    __builtin_amdgcn_global_load_lds((const u16*)(aSrc[j] + k1),
                        (u16*)&As[(cur ^ 1) * BM * BK + aOff[j]], 16, 0, 0);
                #pragma unroll
                for (int j = 0; j < BIW; j++)
                    __builtin_amdgcn_global_load_lds((const u16*)(bSrc[j] + k1),
                        (u16*)&Bs[(cur ^ 1) * BN * BK + bOff[j]], 16, 0, 0);
                vm_wait<NLD>();
            } else {
                vm_wait<0>();
            }
            __builtin_amdgcn_s_barrier();
            __builtin_amdgcn_sched_barrier(0);
            compute_tile(&As[cur * BM * BK], &Bs[cur * BN * BK]);
            __builtin_amdgcn_s_barrier();
        }
    } else {
        // single buffer path
        const int nt = K / BK;
        for (int t = 0; t < nt; t++) {
            const int k0 = t * BK;
            __syncthreads();   // prev tile's reads done before overwrite
            #pragma unroll
            for (int j = 0; j < AIW; j++)
                __builtin_amdgcn_global_load_lds((const u16*)(aSrc[j] + k0),
                                                 (u16*)&As[aOff[j]], 16, 0, 0);
            #pragma unroll
            for (int j = 0; j < BIW; j++)
                __builtin_amdgcn_global_load_lds((const u16*)(bSrc[j] + k0),
                                                 (u16*)&Bs[bOff[j]], 16, 0, 0);
            __syncthreads();   // drain -> tile resident
            compute_tile(As, Bs);
        }
    }

    // epilogue: C row = bm+wm+mi*16+fs*4+i, col = bn+wn+ni*16+fr
    #pragma unroll
    for (int mi = 0; mi < MR; mi++) {
        #pragma unroll
        for (int i = 0; i < 4; i++) {
            int lrow2 = wm + (mi << 4) + (fs << 2) + i;
            int row = bm + lrow2;
            float vv[NR];
            #pragma unroll
            for (int ni = 0; ni < NR; ni++) {
                int ncol = bn + wn + (ni << 4) + fr;
                float v = acc[mi][ni][i];
                if (bias)  v += bias[ncol];
                if (resid) v += resid[(size_t)row * ldc + ncol];
                if (RELU)  v = fmaxf(v, 0.0f);
                vv[ni] = v;
                if (OUTBF) ((u16*)Cout)[(size_t)row * ldc + ncol] = f2b(v);
                else       ((float*)Cout)[(size_t)row * ldc + ncol] = v;
            }
            if (LSE) {
                float mx = vv[0];
                #pragma unroll
                for (int ni = 1; ni < NR; ni++) mx = fmaxf(mx, vv[ni]);
                mx = fmaxf(mx, __shfl_xor(mx, 1));
                mx = fmaxf(mx, __shfl_xor(mx, 2));
                mx = fmaxf(mx, __shfl_xor(mx, 4));
                mx = fmaxf(mx, __shfl_xor(mx, 8));
                float ss = 0.f;
                #pragma unroll
                for (int ni = 0; ni < NR; ni++) ss += __expf(vv[ni] - mx);
                ss += __shfl_xor(ss, 1);
                ss += __shfl_xor(ss, 2);
                ss += __shfl_xor(ss, 4);
                ss += __shfl_xor(ss, 8);
                if (fr == 0) {
                    Rm[lrow2 * 2 + (wn >> 6)] = mx;
                    Rs[lrow2 * 2 + (wn >> 6)] = ss;
                }
            }
        }
    }
    if (LSE) {
        __syncthreads();
        int nbn = N / BN;
        for (int r = tid; r < BM; r += 256) {
            float m0 = Rm[r * 2], m1 = Rm[r * 2 + 1];
            float s0 = Rs[r * 2], s1 = Rs[r * 2 + 1];
            float Mx = fmaxf(m0, m1);
            float Sx = s0 * __expf(m0 - Mx) + s1 * __expf(m1 - Mx);
            pmax[(size_t)(bm + r) * nbn + bnIdx] = Mx;
            psum[(size_t)(bm + r) * nbn + bnIdx] = Sx;
        }
    }
}

// ---------------- lse finalize (fp32 logits in place) ----------------
__global__ __launch_bounds__(256)
void k_lsefin(const float* __restrict__ pmax, const float* __restrict__ psum,
              float* __restrict__ out, int nb)
{
    __shared__ float red[8];
    __shared__ float lsh;
    int row = blockIdx.x;
    int tid = threadIdx.x;
    int lane = tid & 63, wv = tid >> 6;

    float m = -1e30f, s = 0.f;
    if (tid < nb) {
        m = pmax[(size_t)row * nb + tid];
        s = psum[(size_t)row * nb + tid];
    }
    float gm = m;
    #pragma unroll
    for (int off = 32; off; off >>= 1) gm = fmaxf(gm, __shfl_xor(gm, off));
    if (lane == 0) red[wv] = gm;
    __syncthreads();
    gm = fmaxf(fmaxf(red[0], red[1]), fmaxf(red[2], red[3]));

    float c = (tid < nb) ? s * __expf(m - gm) : 0.f;
    #pragma unroll
    for (int off = 32; off; off >>= 1) c += __shfl_xor(c, off);
    if (lane == 0) red[4 + wv] = c;
    __syncthreads();
    if (tid == 0) lsh = gm + logf(red[4] + red[5] + red[6] + red[7]);
    __syncthreads();
    float l = lsh;

    float4* x = (float4*)(out + (size_t)row * VOC_);
    for (int i = tid; i < VOC_ / 4; i += 256) {
        float4 v = x[i];
        v.x -= l; v.y -= l; v.z -= l; v.w -= l;
        x[i] = v;
    }
}

// ---------------- lse finalize (bf16 logits in scratch -> fp32 out) ----------------
__global__ __launch_bounds__(256)
void k_lsefin_bf(const float* __restrict__ pmax, const float* __restrict__ psum,
                 const u16* __restrict__ logits, float* __restrict__ out, int nb)
{
    __shared__ float red[8];
    __shared__ float lsh;
    int row = blockIdx.x;
    int tid = threadIdx.x;
    int lane = tid & 63, wv = tid >> 6;

    float m = -1e30f, s = 0.f;
    if (tid < nb) {
        m = pmax[(size_t)row * nb + tid];
        s = psum[(size_t)row * nb + tid];
    }
    float gm = m;
    #pragma unroll
    for (int off = 32; off; off >>= 1) gm = fmaxf(gm, __shfl_xor(gm, off));
    if (lane == 0) red[wv] = gm;
    __syncthreads();
    gm = fmaxf(fmaxf(red[0], red[1]), fmaxf(red[2], red[3]));

    float c = (tid < nb) ? s * __expf(m - gm) : 0.f;
    #pragma unroll
    for (int off = 32; off; off >>= 1) c += __shfl_xor(c, off);
    if (lane == 0) red[4 + wv] = c;
    __syncthreads();
    if (tid == 0) lsh = gm + logf(red[4] + red[5] + red[6] + red[7]);
    __syncthreads();
    float l = lsh;

    const u16* lr = logits + (size_t)row * VOC_;
    float* x = out + (size_t)row * VOC_;
    for (int i = tid * 8; i < VOC_; i += 256 * 8) {
        int4 pk = *(const int4*)(lr + i);
        unsigned a0 = (unsigned)pk.x, a1 = (unsigned)pk.y;
        unsigned a2 = (unsigned)pk.z, a3 = (unsigned)pk.w;
        float4 o0, o1;
        o0.x = b2f((u16)(a0 & 0xffffu)) - l;  o0.y = b2f((u16)(a0 >> 16)) - l;
        o0.z = b2f((u16)(a1 & 0xffffu)) - l;  o0.w = b2f((u16)(a1 >> 16)) - l;
        o1.x = b2f((u16)(a2 & 0xffffu)) - l;  o1.y = b2f((u16)(a2 >> 16)) - l;
        o1.z = b2f((u16)(a3 & 0xffffu)) - l;  o1.w = b2f((u16)(a3 >> 16)) - l;
        *(float4*)(x + i)     = o0;
        *(float4*)(x + i + 4) = o1;
    }
}

// ---------------- fused flash attention (r18 measured-best QBLK=64 form) ----------------
__global__ __launch_bounds__(256)
void k_fattn(const u16* __restrict__ qkv, int ldq, u16* __restrict__ ctx,
             const int* __restrict__ lengths, int causal)
{
    __shared__ __align__(16) u16 Kls[64 * 64];
    __shared__ __align__(16) u16 Vls[64 * 64];   // V^T: row=d, col=kpos (swizzled)
    __shared__ __align__(16) u16 Pls[4][16 * 64];

    const int bh = blockIdx.y;
    const int b = bh >> 3, hd = bh & 7;
    const int q0 = blockIdx.x << 6;
    const int tid = threadIdx.x;
    const int lane = tid & 63;
    const int w = tid >> 6;
    const int fr = lane & 15, fs = lane >> 4;
    const int g7 = fr & 7;

    const u16* Qp = qkv + (size_t)(b * SEQ + q0 + (w << 4) + fr) * ldq + hd * 64;
    short8 aq[2];
    aq[0] = *(const short8*)(Qp + fs * 8);
    aq[1] = *(const short8*)(Qp + 32 + fs * 8);

    const int len = lengths[b];
    const int ntiles = causal ? (q0 >> 6) + 1 : ((len + 63) >> 6);

    float m[4], l[4];
    f32x4 o[4];
    #pragma unroll
    for (int i = 0; i < 4; i++) { m[i] = -1e30f; l[i] = 0.f; }
    #pragma unroll
    for (int n = 0; n < 4; n++) o[n] = (f32x4){0.f, 0.f, 0.f, 0.f};

    const int srow = tid >> 2;
    const int sc2 = (tid & 3) << 1;
    const u16* Kbase = qkv + 512  + (size_t)(b * SEQ) * ldq + hd * 64;
    const u16* Vbase = qkv + 1024 + (size_t)(b * SEQ) * ldq + hd * 64;

    // prologue: stage tile 0's K/V into named registers
    int4 kA, kB, vA, vB;
    {
        const u16* kr = Kbase + (size_t)srow * ldq;
        kA = *(const int4*)(kr + (sc2 << 3));
        kB = *(const int4*)(kr + (sc2 << 3) + 8);
        const u16* vr = Vbase + (size_t)srow * ldq;
        vA = *(const int4*)(vr + (sc2 << 3));
        vB = *(const int4*)(vr + (sc2 << 3) + 8);
    }

    for (int t = 0; t < ntiles; t++) {
        __syncthreads();   // prev iter's Kls/Vls/Pls consumers done
        {
            *(int4*)&Kls[(srow << 6) + ((sc2 ^ (srow & 7)) << 3)]       = kA;
            *(int4*)&Kls[(srow << 6) + (((sc2 + 1) ^ (srow & 7)) << 3)] = kB;
            int d0 = sc2 << 3;
#define VPUT(j, val) Vls[((d0 + (j)) << 6) + (((srow >> 3) ^ ((j) & 7)) << 3) + (srow & 7)] = (u16)(val)
            VPUT(0,  (unsigned)vA.x); VPUT(1,  ((unsigned)vA.x) >> 16);
            VPUT(2,  (unsigned)vA.y); VPUT(3,  ((unsigned)vA.y) >> 16);
            VPUT(4,  (unsigned)vA.z); VPUT(5,  ((unsigned)vA.z) >> 16);
            VPUT(6,  (unsigned)vA.w); VPUT(7,  ((unsigned)vA.w) >> 16);
            VPUT(8,  (unsigned)vB.x); VPUT(9,  ((unsigned)vB.x) >> 16);
            VPUT(10, (unsigned)vB.y); VPUT(11, ((unsigned)vB.y) >> 16);
            VPUT(12, (unsigned)vB.z); VPUT(13, ((unsigned)vB.z) >> 16);
            VPUT(14, (unsigned)vB.w); VPUT(15, ((unsigned)vB.w) >> 16);
#undef VPUT
        }
        __syncthreads();

        // T14: issue tile t+1's loads NOW; latency hides under QK/softmax/PV
        if (t + 1 < ntiles) {
            const u16* kr = Kbase + (size_t)(((t + 1) << 6) + srow) * ldq;
            kA = *(const int4*)(kr + (sc2 << 3));
            kB = *(const int4*)(kr + (sc2 << 3) + 8);
            const u16* vr = Vbase + (size_t)(((t + 1) << 6) + srow) * ldq;
            vA = *(const int4*)(vr + (sc2 << 3));
            vB = *(const int4*)(vr + (sc2 << 3) + 8);
        }

        f32x4 sf[4];
        #pragma unroll
        for (int n = 0; n < 4; n++) {
            int kr = (n << 4) + fr;
            short8 k0f = *(const short8*)&Kls[(kr << 6) + ((fs ^ g7) << 3)];
            short8 k1f = *(const short8*)&Kls[(kr << 6) + (((4 | fs) ^ g7) << 3)];
            f32x4 z = (f32x4){0.f, 0.f, 0.f, 0.f};
            z = __builtin_amdgcn_mfma_f32_16x16x32_bf16(aq[0], k0f, z, 0, 0, 0);
            z = __builtin_amdgcn_mfma_f32_16x16x32_bf16(aq[1], k1f, z, 0, 0, 0);
            sf[n] = z;
        }
        float tm[4];
        #pragma unroll
        for (int i = 0; i < 4; i++) tm[i] = -1e30f;
        #pragma unroll
        for (int n = 0; n < 4; n++) {
            int kp = (t << 6) + (n << 4) + fr;
            #pragma unroll
            for (int i = 0; i < 4; i++) {
                int qr = q0 + (w << 4) + (fs << 2) + i;
                float v = sf[n][i] * 0.125f;
                bool msk = causal ? (kp > qr) : (kp >= len);
                v = msk ? -1e30f : v;
                sf[n][i] = v;
                tm[i] = fmaxf(tm[i], v);
            }
        }
        #pragma unroll
        for (int i = 0; i < 4; i++) {
            tm[i] = fmaxf(tm[i], __shfl_xor(tm[i], 1));
            tm[i] = fmaxf(tm[i], __shfl_xor(tm[i], 2));
            tm[i] = fmaxf(tm[i], __shfl_xor(tm[i], 4));
            tm[i] = fmaxf(tm[i], __shfl_xor(tm[i], 8));
        }
        float ts[4];
        #pragma unroll
        for (int i = 0; i < 4; i++) {
            float mn = fmaxf(m[i], tm[i]);
            float sc = __expf(m[i] - mn);
            m[i] = mn;
            l[i] *= sc;
            #pragma unroll
            for (int n = 0; n < 4; n++) o[n][i] *= sc;
            ts[i] = 0.f;
        }
        #pragma unroll
        for (int n = 0; n < 4; n++) {
            #pragma unroll
            for (int i = 0; i < 4; i++) {
                float pv = __expf(sf[n][i] - m[i]);
                ts[i] += pv;
                int row = (fs << 2) + i;
                int col = (n << 4) + fr;
                Pls[w][(row << 6) + (((col >> 3) ^ (row & 7)) << 3) + (col & 7)] = f2b(pv);
            }
        }
        #pragma unroll
        for (int i = 0; i < 4; i++) {
            ts[i] += __shfl_xor(ts[i], 1);
            ts[i] += __shfl_xor(ts[i], 2);
            ts[i] += __shfl_xor(ts[i], 4);
            ts[i] += __shfl_xor(ts[i], 8);
            l[i] += ts[i];
        }
        __syncthreads();

        #pragma unroll
        for (int kk = 0; kk < 2; kk++) {
            short8 ap = *(const short8*)&Pls[w][(fr << 6) + ((((kk << 2) | fs) ^ g7) << 3)];
            #pragma unroll
            for (int n = 0; n < 4; n++) {
                int dr = (n << 4) + fr;
                short8 vf = *(const short8*)&Vls[(dr << 6) + ((((kk << 2) | fs) ^ g7) << 3)];
                o[n] = __builtin_amdgcn_mfma_f32_16x16x32_bf16(ap, vf, o[n], 0, 0, 0);
            }
        }
    }

    float inv[4];
    #pragma unroll
    for (int i = 0; i < 4; i++) inv[i] = 1.0f / l[i];
    #pragma unroll
    for (int i = 0; i < 4; i++) {
        size_t base = (size_t)(b * SEQ + q0 + (w << 4) + (fs << 2) + i) * HS_ + hd * 64;
        #pragma unroll
        for (int n = 0; n < 4; n++)
            ctx[base + (n << 4) + fr] = f2b(o[n][i] * inv[i]);
    }
}

} // namespace

extern "C" void kernel_launch(void* const* d_in, const int* in_sizes, int n_in,
                              void* d_out, int out_size, void* d_ws, size_t ws_size,
                              hipStream_t stream)
{
    (void)in_sizes; (void)n_in; (void)out_size;
    const int*   x_tokens = (const int*)d_in[0];
    const int*   lengths  = (const int*)d_in[1];
    const int*   y_tokens = (const int*)d_in[2];
    const float* emb_enc  = (const float*)d_in[3];
    const float* emb_dec  = (const float*)d_in[4];
    const float* eWq  = (const float*)d_in[5];
    const float* eWk  = (const float*)d_in[6];
    const float* eWv  = (const float*)d_in[7];
    const float* eWo  = (const float*)d_in[8];
    const float* eln1g = (const float*)d_in[9];
    const float* eln1b = (const float*)d_in[10];
    const float* eln2g = (const float*)d_in[11];
    const float* eln2b = (const float*)d_in[12];
    const float* eW1  = (const float*)d_in[13];
    const float* eb1  = (const float*)d_in[14];
    const float* eW2  = (const float*)d_in[15];
    const float* eb2  = (const float*)d_in[16];
    const float* dsWq = (const float*)d_in[17];
    const float* dsWk = (const float*)d_in[18];
    const float* dsWv = (const float*)d_in[19];
    const float* dsWo = (const float*)d_in[20];
    const float* dcWq = (const float*)d_in[21];
    const float* dcWk = (const float*)d_in[22];
    const float* dcWv = (const float*)d_in[23];
    const float* dcWo = (const float*)d_in[24];
    const float* dln1g = (const float*)d_in[25];
    const float* dln1b = (const float*)d_in[26];
    const float* dln2g = (const float*)d_in[27];
    const float* dln2b = (const float*)d_in[28];
    const float* dln3g = (const float*)d_in[29];
    const float* dln3b = (const float*)d_in[30];
    const float* dW1  = (const float*)d_in[31];
    const float* db1  = (const float*)d_in[32];
    const float* dW2  = (const float*)d_in[33];
    const float* db2  = (const float*)d_in[34];
    const float* glng = (const float*)d_in[35];
    const float* glnb = (const float*)d_in[36];
    const float* gW   = (const float*)d_in[37];
    const float* gb   = (const float*)d_in[38];

    const size_t MH = (size_t)MT * HS_;              // 1,048,576 floats per state

    float* z    = (float*)d_ws;                      // fp32 encoder state
    float* h    = z + MH;                            // fp32 decoder state
    float* big  = h + MH;                            // vwt (8.192M floats) / ffnb overlay
    u16*  vwt   = (u16*)big;                         // [VOC_][HS_] bf16
    u16*  ffnb  = (u16*)big;                         // [MT][FF_] bf16
    float* pmax = big + (size_t)VOC_ * HS_ / 2;      // [MT][250]
    float* psum = pmax + (size_t)MT * 250;
    u16*  qkvb  = (u16*)(psum + (size_t)MT * 250);   // [MT][1536]
    u16*  hnb   = qkvb + (size_t)MT * 1536;
    u16*  kvb   = hnb + MH;
    u16*  ctxb  = kvb + MH;
    u16*  wtb   = ctxb + MH;                         // 8 MB per-layer weights
    const size_t WTB_SZ = 8 * (size_t)HS_ * HS_ + 2 * (size_t)HS_ * FF_;
    u16*  logitsb = wtb + WTB_SZ;                    // [MT][VOC_] bf16 (optional)

    const size_t need_bytes = (size_t)((char*)(logitsb + (size_t)MT * VOC_) - (char*)d_ws);
    const bool bf_logits = (ws_size >= need_bytes);

    const size_t WHH = (size_t)HS_ * HS_;
    const size_t WHF = (size_t)HS_ * FF_;

    const size_t OF_QKV = 0;
    const size_t OF_WO  = 3 * WHH;
    const size_t OF_CQ  = 4 * WHH;
    const size_t OF_CKV = 5 * WHH;
    const size_t OF_CWO = 7 * WHH;
    const size_t OF_W1  = 8 * WHH;
    const size_t OF_W2  = 8 * WHH + WHF;

// N=512 GEMMs: 32x32 tile (1024 blocks = 4/CU)
#define MMS2(RELU, OUTBF, A, W, BIAS, RES, C, M, N, K, LDC) \
    k_mm<32, 32, 64, 1, RELU, OUTBF, 0, 0><<<dim3((N) / 32, (M) / 32), 256, 0, stream>>>( \
        A, W, BIAS, RES, C, M, N, K, LDC, nullptr, nullptr)
// N>=1024 GEMMs: 32x64 tile
#define MMS(RELU, OUTBF, A, W, BIAS, RES, C, M, N, K, LDC) \
    k_mm<32, 64, 64, 1, RELU, OUTBF, 0, 0><<<dim3((N) / 64, (M) / 32), 256, 0, stream>>>( \
        A, W, BIAS, RES, C, M, N, K, LDC, nullptr, nullptr)
// FFN1: 64x64 tile (1024 blocks = 4/CU)
#define MMF(A, W, BIAS, C, M, N, K, LDC) \
    k_mm<64, 64, 64, 1, 1, 1, 0, 0><<<dim3((N) / 64, (M) / 64), 256, 0, stream>>>( \
        A, W, BIAS, nullptr, C, M, N, K, LDC, nullptr, nullptr)

    auto fattn = [&](const u16* qkv, u16* ctxo, int causal) {
        k_fattn<<<dim3(SEQ / 64, NB * NH_), 256, 0, stream>>>(qkv, 1536, ctxo, lengths, causal);
    };

    auto wconv_enc = [&](int i) {
        WSlots s{};
        const float* srcs[6] = {eWq + i * WHH, eWk + i * WHH, eWv + i * WHH,
                                eWo + i * WHH, eW1 + i * WHF, eW2 + i * WHF};
        size_t dofs[6] = {OF_QKV, OF_QKV + WHH, OF_QKV + 2 * WHH, OF_WO, OF_W1, OF_W2};
        int Ks[6] = {512, 512, 512, 512, 512, 2048};
        int Ns[6] = {512, 512, 512, 512, 2048, 512};
        int tot = 0;
        for (int j = 0; j < 6; j++) {
            s.src[j] = srcs[j]; s.dof[j] = dofs[j];
            s.K[j] = Ks[j]; s.N[j] = Ns[j]; s.ktiles[j] = Ks[j] >> 5;
            s.tstart[j] = tot;
            tot += (Ks[j] >> 5) * (Ns[j] >> 5);
        }
        s.ns = 6;
        k_wtm<<<tot, 256, 0, stream>>>(s, wtb);
    };
    auto wconv_dec = [&](int i) {
        WSlots s{};
        const float* srcs[10] = {dsWq + i * WHH, dsWk + i * WHH, dsWv + i * WHH,
                                 dsWo + i * WHH, dcWq + i * WHH, dcWk + i * WHH,
                                 dcWv + i * WHH, dcWo + i * WHH, dW1 + i * WHF, dW2 + i * WHF};
        size_t dofs[10] = {OF_QKV, OF_QKV + WHH, OF_QKV + 2 * WHH, OF_WO, OF_CQ,
                           OF_CKV, OF_CKV + WHH, OF_CWO, OF_W1, OF_W2};
        int Ks[10] = {512, 512, 512, 512, 512, 512, 512, 512, 512, 2048};
        int Ns[10] = {512, 512, 512, 512, 512, 512, 512, 512, 2048, 512};
        int tot = 0;
        for (int j = 0; j < 10; j++) {
            s.src[j] = srcs[j]; s.dof[j] = dofs[j];
            s.K[j] = Ks[j]; s.N[j] = Ns[j]; s.ktiles[j] = Ks[j] >> 5;
            s.tstart[j] = tot;
            tot += (Ks[j] >> 5) * (Ns[j] >> 5);
        }
        s.ns = 10;
        k_wtm<<<tot, 256, 0, stream>>>(s, wtb);
    };

    // embeddings (enc + dec in one launch)
    k_embed2<<<2 * MT, 256, 0, stream>>>(x_tokens, emb_enc, z, y_tokens, emb_dec, h);

    // ---------------- encoder ----------------
    for (int i = 0; i < NL_; i++) {
        wconv_enc(i);
        k_ln<<<MT / 4, 256, 0, stream>>>(z, eln1g + i * HS_, eln1b + i * HS_, hnb);
        MMS(0, 1, hnb, wtb + OF_QKV, nullptr, nullptr, qkvb, MT, 1536, HS_, 1536);
        fattn(qkvb, ctxb, 0);
        MMS2(0, 0, ctxb, wtb + OF_WO, nullptr, z, z, MT, HS_, HS_, HS_);

        k_ln<<<MT / 4, 256, 0, stream>>>(z, eln2g + i * HS_, eln2b + i * HS_, hnb);
        MMF(hnb, wtb + OF_W1, eb1 + i * FF_, ffnb, MT, FF_, HS_, FF_);
        MMS2(0, 0, ffnb, wtb + OF_W2, eb2 + i * HS_, z, z, MT, HS_, FF_, HS_);
    }

    // ---------------- decoder ----------------
    for (int i = 0; i < NL_; i++) {
        wconv_dec(i);

        // self-attn (causal)
        k_ln<<<MT / 4, 256, 0, stream>>>(h, dln1g + i * HS_, dln1b + i * HS_, hnb);
        MMS(0, 1, hnb, wtb + OF_QKV, nullptr, nullptr, qkvb, MT, 1536, HS_, 1536);
        fattn(qkvb, ctxb, 1);
        MMS2(0, 0, ctxb, wtb + OF_WO, nullptr, h, h, MT, HS_, HS_, HS_);

        // cross-attn (dual LN in one launch: z->kvb and h->hnb, same params)
        k_ln2<<<2 * MT / 4, 256, 0, stream>>>(z, kvb, h, hnb,
                                              dln2g + i * HS_, dln2b + i * HS_);
        MMS2(0, 1, hnb, wtb + OF_CQ, nullptr, nullptr, qkvb, MT, HS_, HS_, 1536);
        MMS(0, 1, kvb, wtb + OF_CKV, nullptr, nullptr, qkvb + 512, MT, 1024, HS_, 1536);
        fattn(qkvb, ctxb, 0);
        MMS2(0, 0, ctxb, wtb + OF_CWO, nullptr, h, h, MT, HS_, HS_, HS_);

        // FFN
        k_ln<<<MT / 4, 256, 0, stream>>>(h, dln3g + i * HS_, dln3b + i * HS_, hnb);
        MMF(hnb, wtb + OF_W1, db1 + i * FF_, ffnb, MT, FF_, HS_, FF_);
        MMS2(0, 0, ffnb, wtb + OF_W2, db2 + i * HS_, h, h, MT, HS_, FF_, HS_);
    }

    // ---------------- generator (GEMM + fused log-softmax partials) ----------------
    k_wt<<<dim3(HS_ / 32, VOC_ / 32), 256, 0, stream>>>(gW, vwt, HS_, VOC_);
    k_ln<<<MT / 4, 256, 0, stream>>>(h, glng, glnb, hnb);
    if (bf_logits) {
        // bf16 logits -> scratch (halves GEMM write + lsefin read traffic);
        // LSE partials computed from fp32 pre-rounding values, so lse is exact.
        k_mm<64, 128, 32, 1, 0, 1, 1, 1><<<(MT / 64) * (VOC_ / 128), 256, 0, stream>>>(
            hnb, vwt, gb, nullptr, logitsb, MT, VOC_, HS_, VOC_, pmax, psum);
        k_lsefin_bf<<<MT, 256, 0, stream>>>(pmax, psum, logitsb, (float*)d_out, VOC_ / 128);
    } else {
        k_mm<64, 128, 32, 1, 0, 0, 1, 1><<<(MT / 64) * (VOC_ / 128), 256, 0, stream>>>(
            hnb, vwt, gb, nullptr, (float*)d_out, MT, VOC_, HS_, VOC_, pmax, psum);
        k_lsefin<<<MT, 256, 0, stream>>>(pmax, psum, (float*)d_out, VOC_ / 128);
    }
#undef MMS
#undef MMS2
#undef MMF
}

// Round 25
// 1541.499 us; speedup vs baseline: 1.0122x; 1.0122x over previous
//
#include <hip/hip_runtime.h>
#include <math.h>

namespace {

constexpr int NB   = 4;
constexpr int SEQ  = 512;
constexpr int HS_  = 512;
constexpr int NH_  = 8;
constexpr int NL_  = 6;
constexpr int FF_  = 2048;
constexpr int VOC_ = 32000;
constexpr int MT   = NB * SEQ;   // 2048 token rows

typedef __attribute__((ext_vector_type(8))) short short8;   // 8 bf16 = 4 VGPRs
typedef __attribute__((ext_vector_type(4))) float f32x4;    // MFMA accumulator
typedef unsigned short u16;

__device__ inline float b2f(u16 u) {
    unsigned i = ((unsigned)u) << 16; float f; __builtin_memcpy(&f, &i, 4); return f;
}
__device__ inline u16 f2b(float f) {
    unsigned i; __builtin_memcpy(&i, &f, 4);
    i += 0x7fffu + ((i >> 16) & 1u);            // round-nearest-even
    return (u16)(i >> 16);
}

template<int N> __device__ __forceinline__ void vm_wait() {
    asm volatile("s_waitcnt vmcnt(%0)" :: "n"(N) : "memory");
}

// ---------------- embedding + sinusoidal PE: enc rows [0,MT), dec rows [MT,2MT) ----------------
__global__ __launch_bounds__(256)
void k_embed2(const int* __restrict__ xtok, const float* __restrict__ eemb, float* __restrict__ zo,
              const int* __restrict__ ytok, const float* __restrict__ demb, float* __restrict__ ho)
{
    int row = blockIdx.x;
    const int* tok; const float* emb; float* out;
    if (row < MT) { tok = xtok; emb = eemb; out = zo; }
    else          { row -= MT; tok = ytok; emb = demb; out = ho; }
    int s = row & (SEQ - 1);
    int t = tok[row];
    const float* e = emb + (size_t)t * HS_;
    float* o = out + (size_t)row * HS_;
    for (int i = threadIdx.x; i < HS_; i += 256) {
        int half = i >> 1;
        float freq = powf(10000.0f, -(float)half / (float)HS_);
        float ang = (float)s * freq;
        float pe = (i & 1) ? cosf(ang) : sinf(ang);
        o[i] = e[i] + pe;
    }
}

// ---------------- layernorm row body: one WAVE per row of 512, bf16 out ----------------
__device__ inline void ln_row(int lane, const float* __restrict__ x, const float* __restrict__ g,
                              const float* __restrict__ b, u16* __restrict__ o)
{
    const float* xp = x + lane * 8;
    float4 u0 = *(const float4*)xp;
    float4 u1 = *(const float4*)(xp + 4);
    float v[8] = {u0.x, u0.y, u0.z, u0.w, u1.x, u1.y, u1.z, u1.w};
    float s = 0.f, s2 = 0.f;
    #pragma unroll
    for (int i = 0; i < 8; i++) { s += v[i]; s2 += v[i] * v[i]; }
    #pragma unroll
    for (int off = 32; off; off >>= 1) { s += __shfl_xor(s, off); s2 += __shfl_xor(s2, off); }
    float mean = s * (1.0f / HS_);
    float var  = s2 * (1.0f / HS_) - mean * mean;
    float rstd = rsqrtf(var + 1e-5f);
    const float* gp = g + lane * 8;
    const float* bp = b + lane * 8;
    float4 g0 = *(const float4*)gp, g1 = *(const float4*)(gp + 4);
    float4 b0 = *(const float4*)bp, b1 = *(const float4*)(bp + 4);
    float gv[8] = {g0.x, g0.y, g0.z, g0.w, g1.x, g1.y, g1.z, g1.w};
    float bv[8] = {b0.x, b0.y, b0.z, b0.w, b1.x, b1.y, b1.z, b1.w};
    unsigned w[4];
    #pragma unroll
    for (int j = 0; j < 4; j++) {
        u16 lo = f2b((v[2*j]   - mean) * rstd * gv[2*j]   + bv[2*j]);
        u16 hi = f2b((v[2*j+1] - mean) * rstd * gv[2*j+1] + bv[2*j+1]);
        w[j] = (unsigned)lo | ((unsigned)hi << 16);
    }
    int4 ov; ov.x = w[0]; ov.y = w[1]; ov.z = w[2]; ov.w = w[3];
    *(int4*)(o + lane * 8) = ov;
}

// 256 threads = 4 waves, 4 rows per block (grid MT/4)
__global__ __launch_bounds__(256)
void k_ln(const float* __restrict__ in, const float* __restrict__ g,
          const float* __restrict__ b, u16* __restrict__ out)
{
    int row = (blockIdx.x << 2) + (threadIdx.x >> 6);
    ln_row(threadIdx.x & 63, in + (size_t)row * HS_, g, b, out + (size_t)row * HS_);
}

// two LN streams (same gamma/beta) in one launch; grid 2*MT/4
__global__ __launch_bounds__(256)
void k_ln2(const float* __restrict__ in1, u16* __restrict__ out1,
           const float* __restrict__ in2, u16* __restrict__ out2,
           const float* __restrict__ g, const float* __restrict__ b)
{
    int row = (blockIdx.x << 2) + (threadIdx.x >> 6);
    int lane = threadIdx.x & 63;
    if (row < MT) ln_row(lane, in1 + (size_t)row * HS_, g, b, out1 + (size_t)row * HS_);
    else {
        row -= MT;
        ln_row(lane, in2 + (size_t)row * HS_, g, b, out2 + (size_t)row * HS_);
    }
}

// ---------------- weight transpose+convert: W[K][N] fp32 -> Wt[N][K] bf16 ----------------
__global__ __launch_bounds__(256)
void k_wt(const float* __restrict__ s0, u16* __restrict__ dst, int K, int N)
{
    __shared__ float L[32][33];
    int k0 = blockIdx.x << 5, n0 = blockIdx.y << 5;
    int t = threadIdx.x;
    int r = t >> 3, c4 = (t & 7) << 2;
    float4 v = *(const float4*)(s0 + (size_t)(k0 + r) * N + n0 + c4);
    L[r][c4 + 0] = v.x; L[r][c4 + 1] = v.y; L[r][c4 + 2] = v.z; L[r][c4 + 3] = v.w;
    __syncthreads();
    int n = t >> 3, kq = (t & 7) << 2;
    ushort4 o;
    o.x = f2b(L[kq + 0][n]);
    o.y = f2b(L[kq + 1][n]);
    o.z = f2b(L[kq + 2][n]);
    o.w = f2b(L[kq + 3][n]);
    *(ushort4*)&dst[(size_t)(n0 + n) * K + k0 + kq] = o;
}

// ---------------- batched weight convert: many mats in one launch ----------------
struct WSlots {
    const float* src[10];
    unsigned long long dof[10];  // dst offset in shorts
    int tstart[10];
    int ktiles[10];
    int K[10];
    int N[10];
    int ns;
};

__global__ __launch_bounds__(256)
void k_wtm(WSlots s, u16* __restrict__ base)
{
    __shared__ float L[32][33];
    int bx = blockIdx.x;
    int j = 0;
    for (int t = 1; t < s.ns; t++) if (bx >= s.tstart[t]) j = t;
    int local = bx - s.tstart[j];
    int kt = s.ktiles[j];
    int k0 = (local % kt) << 5;
    int n0 = (local / kt) << 5;
    const float* src = s.src[j];
    int K = s.K[j], N = s.N[j];
    u16* dst = base + s.dof[j];

    int t = threadIdx.x;
    int r = t >> 3, c4 = (t & 7) << 2;
    float4 v = *(const float4*)(src + (size_t)(k0 + r) * N + n0 + c4);
    L[r][c4 + 0] = v.x; L[r][c4 + 1] = v.y; L[r][c4 + 2] = v.z; L[r][c4 + 3] = v.w;
    __syncthreads();
    int n = t >> 3, kq = (t & 7) << 2;
    ushort4 o;
    o.x = f2b(L[kq + 0][n]);
    o.y = f2b(L[kq + 1][n]);
    o.z = f2b(L[kq + 2][n]);
    o.w = f2b(L[kq + 3][n]);
    *(ushort4*)&dst[(size_t)(n0 + n) * K + k0 + kq] = o;
}

// ---------------- bf16 MFMA GEMM: C[M][N] = A[M][K] @ Wt[N][K]^T ----------------
// DB = prefetch depth: 0 = single-buffer sync, 1 = double-buffer distance-1,
//   2 = triple-buffer distance-2 (vocab only: r24 theory — 1.4us/K-iter >> MFMA
//   time means distance-1 fails to cover loaded-HBM latency).
// Per-dispatch configs (measured): N=512 GEMMs 32x32 (r17); QKV/CKV 32x64 (r16);
//   FFN1 64x64 (r18); vocab 64x128 BK=32 (r23) + XCD swizzle + fused LSE.
// Per-layer wconv kept (r21/r24 lesson: L2 locality-in-time beats traffic math).
// Rule #21: swizzle on per-lane GLOBAL source, LDS written linearly.
template<int BM, int BN, int BK, int DB, int RELU, int OUTBF, int LSE, int SWZ>
__global__ __launch_bounds__(256)
void k_mm(const u16* __restrict__ A, const u16* __restrict__ Wt,
          const float* __restrict__ bias, const float* resid,
          void* Cout, int M, int N, int K, int ldc,
          float* __restrict__ pmax, float* __restrict__ psum)
{
    constexpr int MR = BM / 32;      // frag rows per wave
    constexpr int NR = BN / 32;      // frag cols per wave
    constexpr int RPL = (BK == 64) ? 8 : 16;        // rows per gload_lds (1KB)
    constexpr int AIW = BM / (4 * RPL) ? BM / (4 * RPL) : 1;  // gloads per wave (A)
    constexpr int BIW = BN / (4 * RPL) ? BN / (4 * RPL) : 1;
    constexpr int NLD = AIW + BIW;
    constexpr int RS  = BK;                          // row stride in shorts
    constexpr int NBUF = DB ? DB + 1 : 1;
    __shared__ __align__(16) u16 As[NBUF * BM * BK];
    __shared__ __align__(16) u16 Bs[NBUF * BN * BK];
    __shared__ float Rm[LSE ? BM * 2 : 1];
    __shared__ float Rs[LSE ? BM * 2 : 1];

    const int tid  = threadIdx.x;
    const int lane = tid & 63;
    const int w    = tid >> 6;

    int bm, bn, bnIdx;
    if (SWZ) {
        int q = gridDim.x >> 3;
        int logical = (blockIdx.x & 7) * q + (blockIdx.x >> 3);
        int mtiles = M / BM;
        bnIdx = logical / mtiles;
        bm = (logical % mtiles) * BM;
        bn = bnIdx * BN;
    } else {
        bn = blockIdx.x * BN; bm = blockIdx.y * BM; bnIdx = blockIdx.x;
    }
    const int wm = (w >> 1) * (MR * 16), wn = (w & 1) * (NR * 16);
    const int fr = lane & 15, fs = lane >> 4;

    // staging geometry (per-lane global pre-swizzle, wave-uniform LDS base)
    const int lrow = lane / (BK / 8);                // BK=64: lane>>3, BK=32: lane>>2
    const int lchk = lane & (BK / 8 - 1);            // chunk within row
    constexpr int SWM = BK / 8 - 1;                  // swizzle mask: 7 or 3
    const u16* aSrc[4]; const u16* bSrc[4];
    int aOff[4], bOff[4];
    #pragma unroll
    for (int j = 0; j < AIW; j++) {
        int row = w * (BM / 4) + j * RPL + lrow;
        aSrc[j] = A + (size_t)(bm + row) * K + ((lchk ^ (row & SWM)) << 3);
        aOff[j] = (w * (BM / 4) + j * RPL) * RS;
    }
    #pragma unroll
    for (int j = 0; j < BIW; j++) {
        int row = w * (BN / 4) + j * RPL + lrow;
        bSrc[j] = Wt + (size_t)(bn + row) * K + ((lchk ^ (row & SWM)) << 3);
        bOff[j] = (w * (BN / 4) + j * RPL) * RS;
    }

    f32x4 acc[MR][NR];
    #pragma unroll
    for (int i = 0; i < MR; i++)
        #pragma unroll
        for (int j = 0; j < NR; j++)
            acc[i][j] = (f32x4){0.f, 0.f, 0.f, 0.f};

    auto compute_tile = [&](const u16* Ab, const u16* Bb) {
        #pragma unroll
        for (int kk = 0; kk < BK / 32; kk++) {
            short8 av[MR], bv[NR];
            #pragma unroll
            for (int i = 0; i < MR; i++) {
                int r = wm + (i << 4) + fr;
                int slot = (((kk << 2) | fs) ^ (r & SWM));
                av[i] = *(const short8*)&Ab[r * RS + (slot << 3)];
            }
            #pragma unroll
            for (int i = 0; i < NR; i++) {
                int r = wn + (i << 4) + fr;
                int slot = (((kk << 2) | fs) ^ (r & SWM));
                bv[i] = *(const short8*)&Bb[r * RS + (slot << 3)];
            }
            #pragma unroll
            for (int mi = 0; mi < MR; mi++)
                #pragma unroll
                for (int ni = 0; ni < NR; ni++)
                    acc[mi][ni] = __builtin_amdgcn_mfma_f32_16x16x32_bf16(
                        av[mi], bv[ni], acc[mi][ni], 0, 0, 0);
        }
    };

    if (DB) {
        // N-deep pipeline: prefetch distance DB, counted vmcnt, raw barriers.
        #pragma unroll
        for (int p = 0; p < DB; p++) {
            const int kp = p * BK;
            #pragma unroll
            for (int j = 0; j < AIW; j++)
                __builtin_amdgcn_global_load_lds((const u16*)(aSrc[j] + kp),
                    (u16*)&As[p * BM * BK + aOff[j]], 16, 0, 0);
            #pragma unroll
            for (int j = 0; j < BIW; j++)
                __builtin_amdgcn_global_load_lds((const u16*)(bSrc[j] + kp),
                    (u16*)&Bs[p * BN * BK + bOff[j]], 16, 0, 0);
        }
        const int nt = K / BK;
        int cur = 0;
        for (int t = 0; t < nt; t++) {
            const int nx = t + DB;
            if (nx < nt) {
                int nb = cur + DB; if (nb >= NBUF) nb -= NBUF;
                const int k1 = nx * BK;
                #pragma unroll
                for (int j = 0; j < AIW; j++)
                    __builtin_amdgcn_global_load_lds((const u16*)(aSrc[j] + k1),
                        (u16*)&As[nb * BM * BK + aOff[j]], 16, 0, 0);
                #pragma unroll
                for (int j = 0; j < BIW; j++)
                    __builtin_amdgcn_global_load_lds((const u16*)(bSrc[j] + k1),
                        (u16*)&Bs[nb * BN * BK + bOff[j]], 16, 0, 0);
                vm_wait<DB * NLD>();      // tiles t+1..t+DB may stay in flight
            } else if (DB == 2 && nx == nt) {
                vm_wait<NLD>();           // one tile (nt-1) still in flight
            } else {
                vm_wait<0>();
            }
            __builtin_amdgcn_s_barrier();
            __builtin_amdgcn_sched_barrier(0);
            compute_tile(&As[cur * BM * BK], &Bs[cur * BN * BK]);
            __builtin_amdgcn_s_barrier();
            cur = (cur + 1 == NBUF) ? 0 : cur + 1;
        }
    } else {
        // single buffer path
        const int nt = K / BK;
        for (int t = 0; t < nt; t++) {
            const int k0 = t * BK;
            __syncthreads();   // prev tile's reads done before overwrite
            #pragma unroll
            for (int j = 0; j < AIW; j++)
                __builtin_amdgcn_global_load_lds((const u16*)(aSrc[j] + k0),
                                                 (u16*)&As[aOff[j]], 16, 0, 0);
            #pragma unroll
            for (int j = 0; j < BIW; j++)
                __builtin_amdgcn_global_load_lds((const u16*)(bSrc[j] + k0),
                                                 (u16*)&Bs[bOff[j]], 16, 0, 0);
            __syncthreads();   // drain -> tile resident
            compute_tile(As, Bs);
        }
    }

    // epilogue: C row = bm+wm+mi*16+fs*4+i, col = bn+wn+ni*16+fr
    #pragma unroll
    for (int mi = 0; mi < MR; mi++) {
        #pragma unroll
        for (int i = 0; i < 4; i++) {
            int lrow2 = wm + (mi << 4) + (fs << 2) + i;
            int row = bm + lrow2;
            float vv[NR];
            #pragma unroll
            for (int ni = 0; ni < NR; ni++) {
                int ncol = bn + wn + (ni << 4) + fr;
                float v = acc[mi][ni][i];
                if (bias)  v += bias[ncol];
                if (resid) v += resid[(size_t)row * ldc + ncol];
                if (RELU)  v = fmaxf(v, 0.0f);
                vv[ni] = v;
                if (OUTBF) ((u16*)Cout)[(size_t)row * ldc + ncol] = f2b(v);
                else       ((float*)Cout)[(size_t)row * ldc + ncol] = v;
            }
            if (LSE) {
                float mx = vv[0];
                #pragma unroll
                for (int ni = 1; ni < NR; ni++) mx = fmaxf(mx, vv[ni]);
                mx = fmaxf(mx, __shfl_xor(mx, 1));
                mx = fmaxf(mx, __shfl_xor(mx, 2));
                mx = fmaxf(mx, __shfl_xor(mx, 4));
                mx = fmaxf(mx, __shfl_xor(mx, 8));
                float ss = 0.f;
                #pragma unroll
                for (int ni = 0; ni < NR; ni++) ss += __expf(vv[ni] - mx);
                ss += __shfl_xor(ss, 1);
                ss += __shfl_xor(ss, 2);
                ss += __shfl_xor(ss, 4);
                ss += __shfl_xor(ss, 8);
                if (fr == 0) {
                    Rm[lrow2 * 2 + (wn >> 6)] = mx;
                    Rs[lrow2 * 2 + (wn >> 6)] = ss;
                }
            }
        }
    }
    if (LSE) {
        __syncthreads();
        int nbn = N / BN;
        for (int r = tid; r < BM; r += 256) {
            float m0 = Rm[r * 2], m1 = Rm[r * 2 + 1];
            float s0 = Rs[r * 2], s1 = Rs[r * 2 + 1];
            float Mx = fmaxf(m0, m1);
            float Sx = s0 * __expf(m0 - Mx) + s1 * __expf(m1 - Mx);
            pmax[(size_t)(bm + r) * nbn + bnIdx] = Mx;
            psum[(size_t)(bm + r) * nbn + bnIdx] = Sx;
        }
    }
}

// ---------------- lse finalize: reduce partials + subtract in place ----------------
// In-place RMW on d_out is deliberate (r24 lesson): GEMM-written lines are
// L2-dirty; read+write-hit runs ~5 TB/s vs 2 TB/s for a two-stream variant.
__global__ __launch_bounds__(256)
void k_lsefin(const float* __restrict__ pmax, const float* __restrict__ psum,
              float* __restrict__ out, int nb)
{
    __shared__ float red[8];
    __shared__ float lsh;
    int row = blockIdx.x;
    int tid = threadIdx.x;
    int lane = tid & 63, wv = tid >> 6;

    float m = -1e30f, s = 0.f;
    if (tid < nb) {
        m = pmax[(size_t)row * nb + tid];
        s = psum[(size_t)row * nb + tid];
    }
    float gm = m;
    #pragma unroll
    for (int off = 32; off; off >>= 1) gm = fmaxf(gm, __shfl_xor(gm, off));
    if (lane == 0) red[wv] = gm;
    __syncthreads();
    gm = fmaxf(fmaxf(red[0], red[1]), fmaxf(red[2], red[3]));

    float c = (tid < nb) ? s * __expf(m - gm) : 0.f;
    #pragma unroll
    for (int off = 32; off; off >>= 1) c += __shfl_xor(c, off);
    if (lane == 0) red[4 + wv] = c;
    __syncthreads();
    if (tid == 0) lsh = gm + logf(red[4] + red[5] + red[6] + red[7]);
    __syncthreads();
    float l = lsh;

    float4* x = (float4*)(out + (size_t)row * VOC_);
    for (int i = tid; i < VOC_ / 4; i += 256) {
        float4 v = x[i];
        v.x -= l; v.y -= l; v.z -= l; v.w -= l;
        x[i] = v;
    }
}

// ---------------- fused flash attention (r18 measured-best QBLK=64 form) ----------------
__global__ __launch_bounds__(256)
void k_fattn(const u16* __restrict__ qkv, int ldq, u16* __restrict__ ctx,
             const int* __restrict__ lengths, int causal)
{
    __shared__ __align__(16) u16 Kls[64 * 64];
    __shared__ __align__(16) u16 Vls[64 * 64];   // V^T: row=d, col=kpos (swizzled)
    __shared__ __align__(16) u16 Pls[4][16 * 64];

    const int bh = blockIdx.y;
    const int b = bh >> 3, hd = bh & 7;
    const int q0 = blockIdx.x << 6;
    const int tid = threadIdx.x;
    const int lane = tid & 63;
    const int w = tid >> 6;
    const int fr = lane & 15, fs = lane >> 4;
    const int g7 = fr & 7;

    const u16* Qp = qkv + (size_t)(b * SEQ + q0 + (w << 4) + fr) * ldq + hd * 64;
    short8 aq[2];
    aq[0] = *(const short8*)(Qp + fs * 8);
    aq[1] = *(const short8*)(Qp + 32 + fs * 8);

    const int len = lengths[b];
    const int ntiles = causal ? (q0 >> 6) + 1 : ((len + 63) >> 6);

    float m[4], l[4];
    f32x4 o[4];
    #pragma unroll
    for (int i = 0; i < 4; i++) { m[i] = -1e30f; l[i] = 0.f; }
    #pragma unroll
    for (int n = 0; n < 4; n++) o[n] = (f32x4){0.f, 0.f, 0.f, 0.f};

    const int srow = tid >> 2;
    const int sc2 = (tid & 3) << 1;
    const u16* Kbase = qkv + 512  + (size_t)(b * SEQ) * ldq + hd * 64;
    const u16* Vbase = qkv + 1024 + (size_t)(b * SEQ) * ldq + hd * 64;

    // prologue: stage tile 0's K/V into named registers
    int4 kA, kB, vA, vB;
    {
        const u16* kr = Kbase + (size_t)srow * ldq;
        kA = *(const int4*)(kr + (sc2 << 3));
        kB = *(const int4*)(kr + (sc2 << 3) + 8);
        const u16* vr = Vbase + (size_t)srow * ldq;
        vA = *(const int4*)(vr + (sc2 << 3));
        vB = *(const int4*)(vr + (sc2 << 3) + 8);
    }

    for (int t = 0; t < ntiles; t++) {
        __syncthreads();   // prev iter's Kls/Vls/Pls consumers done
        {
            *(int4*)&Kls[(srow << 6) + ((sc2 ^ (srow & 7)) << 3)]       = kA;
            *(int4*)&Kls[(srow << 6) + (((sc2 + 1) ^ (srow & 7)) << 3)] = kB;
            int d0 = sc2 << 3;
#define VPUT(j, val) Vls[((d0 + (j)) << 6) + (((srow >> 3) ^ ((j) & 7)) << 3) + (srow & 7)] = (u16)(val)
            VPUT(0,  (unsigned)vA.x); VPUT(1,  ((unsigned)vA.x) >> 16);
            VPUT(2,  (unsigned)vA.y); VPUT(3,  ((unsigned)vA.y) >> 16);
            VPUT(4,  (unsigned)vA.z); VPUT(5,  ((unsigned)vA.z) >> 16);
            VPUT(6,  (unsigned)vA.w); VPUT(7,  ((unsigned)vA.w) >> 16);
            VPUT(8,  (unsigned)vB.x); VPUT(9,  ((unsigned)vB.x) >> 16);
            VPUT(10, (unsigned)vB.y); VPUT(11, ((unsigned)vB.y) >> 16);
            VPUT(12, (unsigned)vB.z); VPUT(13, ((unsigned)vB.z) >> 16);
            VPUT(14, (unsigned)vB.w); VPUT(15, ((unsigned)vB.w) >> 16);
#undef VPUT
        }
        __syncthreads();

        // T14: issue tile t+1's loads NOW; latency hides under QK/softmax/PV
        if (t + 1 < ntiles) {
            const u16* kr = Kbase + (size_t)(((t + 1) << 6) + srow) * ldq;
            kA = *(const int4*)(kr + (sc2 << 3));
            kB = *(const int4*)(kr + (sc2 << 3) + 8);
            const u16* vr = Vbase + (size_t)(((t + 1) << 6) + srow) * ldq;
            vA = *(const int4*)(vr + (sc2 << 3));
            vB = *(const int4*)(vr + (sc2 << 3) + 8);
        }

        f32x4 sf[4];
        #pragma unroll
        for (int n = 0; n < 4; n++) {
            int kr = (n << 4) + fr;
            short8 k0f = *(const short8*)&Kls[(kr << 6) + ((fs ^ g7) << 3)];
            short8 k1f = *(const short8*)&Kls[(kr << 6) + (((4 | fs) ^ g7) << 3)];
            f32x4 z = (f32x4){0.f, 0.f, 0.f, 0.f};
            z = __builtin_amdgcn_mfma_f32_16x16x32_bf16(aq[0], k0f, z, 0, 0, 0);
            z = __builtin_amdgcn_mfma_f32_16x16x32_bf16(aq[1], k1f, z, 0, 0, 0);
            sf[n] = z;
        }
        float tm[4];
        #pragma unroll
        for (int i = 0; i < 4; i++) tm[i] = -1e30f;
        #pragma unroll
        for (int n = 0; n < 4; n++) {
            int kp = (t << 6) + (n << 4) + fr;
            #pragma unroll
            for (int i = 0; i < 4; i++) {
                int qr = q0 + (w << 4) + (fs << 2) + i;
                float v = sf[n][i] * 0.125f;
                bool msk = causal ? (kp > qr) : (kp >= len);
                v = msk ? -1e30f : v;
                sf[n][i] = v;
                tm[i] = fmaxf(tm[i], v);
            }
        }
        #pragma unroll
        for (int i = 0; i < 4; i++) {
            tm[i] = fmaxf(tm[i], __shfl_xor(tm[i], 1));
            tm[i] = fmaxf(tm[i], __shfl_xor(tm[i], 2));
            tm[i] = fmaxf(tm[i], __shfl_xor(tm[i], 4));
            tm[i] = fmaxf(tm[i], __shfl_xor(tm[i], 8));
        }
        float ts[4];
        #pragma unroll
        for (int i = 0; i < 4; i++) {
            float mn = fmaxf(m[i], tm[i]);
            float sc = __expf(m[i] - mn);
            m[i] = mn;
            l[i] *= sc;
            #pragma unroll
            for (int n = 0; n < 4; n++) o[n][i] *= sc;
            ts[i] = 0.f;
        }
        #pragma unroll
        for (int n = 0; n < 4; n++) {
            #pragma unroll
            for (int i = 0; i < 4; i++) {
                float pv = __expf(sf[n][i] - m[i]);
                ts[i] += pv;
                int row = (fs << 2) + i;
                int col = (n << 4) + fr;
                Pls[w][(row << 6) + (((col >> 3) ^ (row & 7)) << 3) + (col & 7)] = f2b(pv);
            }
        }
        #pragma unroll
        for (int i = 0; i < 4; i++) {
            ts[i] += __shfl_xor(ts[i], 1);
            ts[i] += __shfl_xor(ts[i], 2);
            ts[i] += __shfl_xor(ts[i], 4);
            ts[i] += __shfl_xor(ts[i], 8);
            l[i] += ts[i];
        }
        __syncthreads();

        #pragma unroll
        for (int kk = 0; kk < 2; kk++) {
            short8 ap = *(const short8*)&Pls[w][(fr << 6) + ((((kk << 2) | fs) ^ g7) << 3)];
            #pragma unroll
            for (int n = 0; n < 4; n++) {
                int dr = (n << 4) + fr;
                short8 vf = *(const short8*)&Vls[(dr << 6) + ((((kk << 2) | fs) ^ g7) << 3)];
                o[n] = __builtin_amdgcn_mfma_f32_16x16x32_bf16(ap, vf, o[n], 0, 0, 0);
            }
        }
    }

    float inv[4];
    #pragma unroll
    for (int i = 0; i < 4; i++) inv[i] = 1.0f / l[i];
    #pragma unroll
    for (int i = 0; i < 4; i++) {
        size_t base = (size_t)(b * SEQ + q0 + (w << 4) + (fs << 2) + i) * HS_ + hd * 64;
        #pragma unroll
        for (int n = 0; n < 4; n++)
            ctx[base + (n << 4) + fr] = f2b(o[n][i] * inv[i]);
    }
}

} // namespace

extern "C" void kernel_launch(void* const* d_in, const int* in_sizes, int n_in,
                              void* d_out, int out_size, void* d_ws, size_t ws_size,
                              hipStream_t stream)
{
    (void)in_sizes; (void)n_in; (void)out_size; (void)ws_size;
    const int*   x_tokens = (const int*)d_in[0];
    const int*   lengths  = (const int*)d_in[1];
    const int*   y_tokens = (const int*)d_in[2];
    const float* emb_enc  = (const float*)d_in[3];
    const float* emb_dec  = (const float*)d_in[4];
    const float* eWq  = (const float*)d_in[5];
    const float* eWk  = (const float*)d_in[6];
    const float* eWv  = (const float*)d_in[7];
    const float* eWo  = (const float*)d_in[8];
    const float* eln1g = (const float*)d_in[9];
    const float* eln1b = (const float*)d_in[10];
    const float* eln2g = (const float*)d_in[11];
    const float* eln2b = (const float*)d_in[12];
    const float* eW1  = (const float*)d_in[13];
    const float* eb1  = (const float*)d_in[14];
    const float* eW2  = (const float*)d_in[15];
    const float* eb2  = (const float*)d_in[16];
    const float* dsWq = (const float*)d_in[17];
    const float* dsWk = (const float*)d_in[18];
    const float* dsWv = (const float*)d_in[19];
    const float* dsWo = (const float*)d_in[20];
    const float* dcWq = (const float*)d_in[21];
    const float* dcWk = (const float*)d_in[22];
    const float* dcWv = (const float*)d_in[23];
    const float* dcWo = (const float*)d_in[24];
    const float* dln1g = (const float*)d_in[25];
    const float* dln1b = (const float*)d_in[26];
    const float* dln2g = (const float*)d_in[27];
    const float* dln2b = (const float*)d_in[28];
    const float* dln3g = (const float*)d_in[29];
    const float* dln3b = (const float*)d_in[30];
    const float* dW1  = (const float*)d_in[31];
    const float* db1  = (const float*)d_in[32];
    const float* dW2  = (const float*)d_in[33];
    const float* db2  = (const float*)d_in[34];
    const float* glng = (const float*)d_in[35];
    const float* glnb = (const float*)d_in[36];
    const float* gW   = (const float*)d_in[37];
    const float* gb   = (const float*)d_in[38];

    const size_t MH = (size_t)MT * HS_;              // 1,048,576 floats per state

    float* z    = (float*)d_ws;                      // fp32 encoder state
    float* h    = z + MH;                            // fp32 decoder state
    float* big  = h + MH;                            // vwt (8.192M floats) / ffnb overlay
    u16*  vwt   = (u16*)big;                         // [VOC_][HS_] bf16
    u16*  ffnb  = (u16*)big;                         // [MT][FF_] bf16
    float* pmax = big + (size_t)VOC_ * HS_ / 2;      // [MT][250]
    float* psum = pmax + (size_t)MT * 250;
    u16*  qkvb  = (u16*)(psum + (size_t)MT * 250);   // [MT][1536]
    u16*  hnb   = qkvb + (size_t)MT * 1536;
    u16*  kvb   = hnb + MH;
    u16*  ctxb  = kvb + MH;
    u16*  wtb   = ctxb + MH;                         // 8 MB per-layer weights

    const size_t WHH = (size_t)HS_ * HS_;
    const size_t WHF = (size_t)HS_ * FF_;

    const size_t OF_QKV = 0;
    const size_t OF_WO  = 3 * WHH;
    const size_t OF_CQ  = 4 * WHH;
    const size_t OF_CKV = 5 * WHH;
    const size_t OF_CWO = 7 * WHH;
    const size_t OF_W1  = 8 * WHH;
    const size_t OF_W2  = 8 * WHH + WHF;

// N=512 GEMMs: 32x32 tile (1024 blocks = 4/CU)
#define MMS2(RELU, OUTBF, A, W, BIAS, RES, C, M, N, K, LDC) \
    k_mm<32, 32, 64, 1, RELU, OUTBF, 0, 0><<<dim3((N) / 32, (M) / 32), 256, 0, stream>>>( \
        A, W, BIAS, RES, C, M, N, K, LDC, nullptr, nullptr)
// N>=1024 GEMMs: 32x64 tile
#define MMS(RELU, OUTBF, A, W, BIAS, RES, C, M, N, K, LDC) \
    k_mm<32, 64, 64, 1, RELU, OUTBF, 0, 0><<<dim3((N) / 64, (M) / 32), 256, 0, stream>>>( \
        A, W, BIAS, RES, C, M, N, K, LDC, nullptr, nullptr)
// FFN1: 64x64 tile (1024 blocks = 4/CU)
#define MMF(A, W, BIAS, C, M, N, K, LDC) \
    k_mm<64, 64, 64, 1, 1, 1, 0, 0><<<dim3((N) / 64, (M) / 64), 256, 0, stream>>>( \
        A, W, BIAS, nullptr, C, M, N, K, LDC, nullptr, nullptr)

    auto fattn = [&](const u16* qkv, u16* ctxo, int causal) {
        k_fattn<<<dim3(SEQ / 64, NB * NH_), 256, 0, stream>>>(qkv, 1536, ctxo, lengths, causal);
    };

    auto wconv_enc = [&](int i) {
        WSlots s{};
        const float* srcs[6] = {eWq + i * WHH, eWk + i * WHH, eWv + i * WHH,
                                eWo + i * WHH, eW1 + i * WHF, eW2 + i * WHF};
        size_t dofs[6] = {OF_QKV, OF_QKV + WHH, OF_QKV + 2 * WHH, OF_WO, OF_W1, OF_W2};
        int Ks[6] = {512, 512, 512, 512, 512, 2048};
        int Ns[6] = {512, 512, 512, 512, 2048, 512};
        int tot = 0;
        for (int j = 0; j < 6; j++) {
            s.src[j] = srcs[j]; s.dof[j] = dofs[j];
            s.K[j] = Ks[j]; s.N[j] = Ns[j]; s.ktiles[j] = Ks[j] >> 5;
            s.tstart[j] = tot;
            tot += (Ks[j] >> 5) * (Ns[j] >> 5);
        }
        s.ns = 6;
        k_wtm<<<tot, 256, 0, stream>>>(s, wtb);
    };
    auto wconv_dec = [&](int i) {
        WSlots s{};
        const float* srcs[10] = {dsWq + i * WHH, dsWk + i * WHH, dsWv + i * WHH,
                                 dsWo + i * WHH, dcWq + i * WHH, dcWk + i * WHH,
                                 dcWv + i * WHH, dcWo + i * WHH, dW1 + i * WHF, dW2 + i * WHF};
        size_t dofs[10] = {OF_QKV, OF_QKV + WHH, OF_QKV + 2 * WHH, OF_WO, OF_CQ,
                           OF_CKV, OF_CKV + WHH, OF_CWO, OF_W1, OF_W2};
        int Ks[10] = {512, 512, 512, 512, 512, 512, 512, 512, 512, 2048};
        int Ns[10] = {512, 512, 512, 512, 512, 512, 512, 512, 2048, 512};
        int tot = 0;
        for (int j = 0; j < 10; j++) {
            s.src[j] = srcs[j]; s.dof[j] = dofs[j];
            s.K[j] = Ks[j]; s.N[j] = Ns[j]; s.ktiles[j] = Ks[j] >> 5;
            s.tstart[j] = tot;
            tot += (Ks[j] >> 5) * (Ns[j] >> 5);
        }
        s.ns = 10;
        k_wtm<<<tot, 256, 0, stream>>>(s, wtb);
    };

    // embeddings (enc + dec in one launch)
    k_embed2<<<2 * MT, 256, 0, stream>>>(x_tokens, emb_enc, z, y_tokens, emb_dec, h);

    // ---------------- encoder ----------------
    for (int i = 0; i < NL_; i++) {
        wconv_enc(i);
        k_ln<<<MT / 4, 256, 0, stream>>>(z, eln1g + i * HS_, eln1b + i * HS_, hnb);
        MMS(0, 1, hnb, wtb + OF_QKV, nullptr, nullptr, qkvb, MT, 1536, HS_, 1536);
        fattn(qkvb, ctxb, 0);
        MMS2(0, 0, ctxb, wtb + OF_WO, nullptr, z, z, MT, HS_, HS_, HS_);

        k_ln<<<MT / 4, 256, 0, stream>>>(z, eln2g + i * HS_, eln2b + i * HS_, hnb);
        MMF(hnb, wtb + OF_W1, eb1 + i * FF_, ffnb, MT, FF_, HS_, FF_);
        MMS2(0, 0, ffnb, wtb + OF_W2, eb2 + i * HS_, z, z, MT, HS_, FF_, HS_);
    }

    // ---------------- decoder ----------------
    for (int i = 0; i < NL_; i++) {
        wconv_dec(i);

        // self-attn (causal)
        k_ln<<<MT / 4, 256, 0, stream>>>(h, dln1g + i * HS_, dln1b + i * HS_, hnb);
        MMS(0, 1, hnb, wtb + OF_QKV, nullptr, nullptr, qkvb, MT, 1536, HS_, 1536);
        fattn(qkvb, ctxb, 1);
        MMS2(0, 0, ctxb, wtb + OF_WO, nullptr, h, h, MT, HS_, HS_, HS_);

        // cross-attn (dual LN in one launch: z->kvb and h->hnb, same params)
        k_ln2<<<2 * MT / 4, 256, 0, stream>>>(z, kvb, h, hnb,
                                              dln2g + i * HS_, dln2b + i * HS_);
        MMS2(0, 1, hnb, wtb + OF_CQ, nullptr, nullptr, qkvb, MT, HS_, HS_, 1536);
        MMS(0, 1, kvb, wtb + OF_CKV, nullptr, nullptr, qkvb + 512, MT, 1024, HS_, 1536);
        fattn(qkvb, ctxb, 0);
        MMS2(0, 0, ctxb, wtb + OF_CWO, nullptr, h, h, MT, HS_, HS_, HS_);

        // FFN
        k_ln<<<MT / 4, 256, 0, stream>>>(h, dln3g + i * HS_, dln3b + i * HS_, hnb);
        MMF(hnb, wtb + OF_W1, db1 + i * FF_, ffnb, MT, FF_, HS_, FF_);
        MMS2(0, 0, ffnb, wtb + OF_W2, db2 + i * HS_, h, h, MT, HS_, FF_, HS_);
    }

    // ---------------- generator (GEMM + fused log-softmax partials) ----------------
    k_wt<<<dim3(HS_ / 32, VOC_ / 32), 256, 0, stream>>>(gW, vwt, HS_, VOC_);
    k_ln<<<MT / 4, 256, 0, stream>>>(h, glng, glnb, hnb);
    // vocab: 64x128 BK=32, DB=2 (distance-2 prefetch, 37KB LDS, same 4 blk/CU)
    k_mm<64, 128, 32, 2, 0, 0, 1, 1><<<(MT / 64) * (VOC_ / 128), 256, 0, stream>>>(
        hnb, vwt, gb, nullptr, (float*)d_out, MT, VOC_, HS_, VOC_, pmax, psum);
    k_lsefin<<<MT, 256, 0, stream>>>(pmax, psum, (float*)d_out, VOC_ / 128);
#undef MMS
#undef MMS2
#undef MMF
}

// Round 26
// 1510.206 us; speedup vs baseline: 1.0332x; 1.0207x over previous
//
#include <hip/hip_runtime.h>
#include <math.h>

namespace {

constexpr int NB   = 4;
constexpr int SEQ  = 512;
constexpr int HS_  = 512;
constexpr int NH_  = 8;
constexpr int NL_  = 6;
constexpr int FF_  = 2048;
constexpr int VOC_ = 32000;
constexpr int MT   = NB * SEQ;   // 2048 token rows

typedef __attribute__((ext_vector_type(8))) short short8;   // 8 bf16 = 4 VGPRs
typedef __attribute__((ext_vector_type(4))) float f32x4;    // MFMA accumulator
typedef unsigned short u16;

__device__ inline float b2f(u16 u) {
    unsigned i = ((unsigned)u) << 16; float f; __builtin_memcpy(&f, &i, 4); return f;
}
__device__ inline u16 f2b(float f) {
    unsigned i; __builtin_memcpy(&i, &f, 4);
    i += 0x7fffu + ((i >> 16) & 1u);            // round-nearest-even
    return (u16)(i >> 16);
}

template<int N> __device__ __forceinline__ void vm_wait() {
    asm volatile("s_waitcnt vmcnt(%0)" :: "n"(N) : "memory");
}

// ---------------- embedding + sinusoidal PE: enc rows [0,MT), dec rows [MT,2MT) ----------------
__global__ __launch_bounds__(256)
void k_embed2(const int* __restrict__ xtok, const float* __restrict__ eemb, float* __restrict__ zo,
              const int* __restrict__ ytok, const float* __restrict__ demb, float* __restrict__ ho)
{
    int row = blockIdx.x;
    const int* tok; const float* emb; float* out;
    if (row < MT) { tok = xtok; emb = eemb; out = zo; }
    else          { row -= MT; tok = ytok; emb = demb; out = ho; }
    int s = row & (SEQ - 1);
    int t = tok[row];
    const float* e = emb + (size_t)t * HS_;
    float* o = out + (size_t)row * HS_;
    for (int i = threadIdx.x; i < HS_; i += 256) {
        int half = i >> 1;
        float freq = powf(10000.0f, -(float)half / (float)HS_);
        float ang = (float)s * freq;
        float pe = (i & 1) ? cosf(ang) : sinf(ang);
        o[i] = e[i] + pe;
    }
}

// ---------------- layernorm row body: one WAVE per row of 512, bf16 out ----------------
__device__ inline void ln_row(int lane, const float* __restrict__ x, const float* __restrict__ g,
                              const float* __restrict__ b, u16* __restrict__ o)
{
    const float* xp = x + lane * 8;
    float4 u0 = *(const float4*)xp;
    float4 u1 = *(const float4*)(xp + 4);
    float v[8] = {u0.x, u0.y, u0.z, u0.w, u1.x, u1.y, u1.z, u1.w};
    float s = 0.f, s2 = 0.f;
    #pragma unroll
    for (int i = 0; i < 8; i++) { s += v[i]; s2 += v[i] * v[i]; }
    #pragma unroll
    for (int off = 32; off; off >>= 1) { s += __shfl_xor(s, off); s2 += __shfl_xor(s2, off); }
    float mean = s * (1.0f / HS_);
    float var  = s2 * (1.0f / HS_) - mean * mean;
    float rstd = rsqrtf(var + 1e-5f);
    const float* gp = g + lane * 8;
    const float* bp = b + lane * 8;
    float4 g0 = *(const float4*)gp, g1 = *(const float4*)(gp + 4);
    float4 b0 = *(const float4*)bp, b1 = *(const float4*)(bp + 4);
    float gv[8] = {g0.x, g0.y, g0.z, g0.w, g1.x, g1.y, g1.z, g1.w};
    float bv[8] = {b0.x, b0.y, b0.z, b0.w, b1.x, b1.y, b1.z, b1.w};
    unsigned w[4];
    #pragma unroll
    for (int j = 0; j < 4; j++) {
        u16 lo = f2b((v[2*j]   - mean) * rstd * gv[2*j]   + bv[2*j]);
        u16 hi = f2b((v[2*j+1] - mean) * rstd * gv[2*j+1] + bv[2*j+1]);
        w[j] = (unsigned)lo | ((unsigned)hi << 16);
    }
    int4 ov; ov.x = w[0]; ov.y = w[1]; ov.z = w[2]; ov.w = w[3];
    *(int4*)(o + lane * 8) = ov;
}

// 256 threads = 4 waves, 4 rows per block (grid MT/4)
__global__ __launch_bounds__(256)
void k_ln(const float* __restrict__ in, const float* __restrict__ g,
          const float* __restrict__ b, u16* __restrict__ out)
{
    int row = (blockIdx.x << 2) + (threadIdx.x >> 6);
    ln_row(threadIdx.x & 63, in + (size_t)row * HS_, g, b, out + (size_t)row * HS_);
}

// two LN streams (same gamma/beta) in one launch; grid 2*MT/4
__global__ __launch_bounds__(256)
void k_ln2(const float* __restrict__ in1, u16* __restrict__ out1,
           const float* __restrict__ in2, u16* __restrict__ out2,
           const float* __restrict__ g, const float* __restrict__ b)
{
    int row = (blockIdx.x << 2) + (threadIdx.x >> 6);
    int lane = threadIdx.x & 63;
    if (row < MT) ln_row(lane, in1 + (size_t)row * HS_, g, b, out1 + (size_t)row * HS_);
    else {
        row -= MT;
        ln_row(lane, in2 + (size_t)row * HS_, g, b, out2 + (size_t)row * HS_);
    }
}

// ---------------- weight transpose+convert: W[K][N] fp32 -> Wt[N][K] bf16 ----------------
__global__ __launch_bounds__(256)
void k_wt(const float* __restrict__ s0, u16* __restrict__ dst, int K, int N)
{
    __shared__ float L[32][33];
    int k0 = blockIdx.x << 5, n0 = blockIdx.y << 5;
    int t = threadIdx.x;
    int r = t >> 3, c4 = (t & 7) << 2;
    float4 v = *(const float4*)(s0 + (size_t)(k0 + r) * N + n0 + c4);
    L[r][c4 + 0] = v.x; L[r][c4 + 1] = v.y; L[r][c4 + 2] = v.z; L[r][c4 + 3] = v.w;
    __syncthreads();
    int n = t >> 3, kq = (t & 7) << 2;
    ushort4 o;
    o.x = f2b(L[kq + 0][n]);
    o.y = f2b(L[kq + 1][n]);
    o.z = f2b(L[kq + 2][n]);
    o.w = f2b(L[kq + 3][n]);
    *(ushort4*)&dst[(size_t)(n0 + n) * K + k0 + kq] = o;
}

// ---------------- batched weight convert: many mats in one launch ----------------
struct WSlots {
    const float* src[10];
    unsigned long long dof[10];  // dst offset in shorts
    int tstart[10];
    int ktiles[10];
    int K[10];
    int N[10];
    int ns;
};

__global__ __launch_bounds__(256)
void k_wtm(WSlots s, u16* __restrict__ base)
{
    __shared__ float L[32][33];
    int bx = blockIdx.x;
    int j = 0;
    for (int t = 1; t < s.ns; t++) if (bx >= s.tstart[t]) j = t;
    int local = bx - s.tstart[j];
    int kt = s.ktiles[j];
    int k0 = (local % kt) << 5;
    int n0 = (local / kt) << 5;
    const float* src = s.src[j];
    int K = s.K[j], N = s.N[j];
    u16* dst = base + s.dof[j];

    int t = threadIdx.x;
    int r = t >> 3, c4 = (t & 7) << 2;
    float4 v = *(const float4*)(src + (size_t)(k0 + r) * N + n0 + c4);
    L[r][c4 + 0] = v.x; L[r][c4 + 1] = v.y; L[r][c4 + 2] = v.z; L[r][c4 + 3] = v.w;
    __syncthreads();
    int n = t >> 3, kq = (t & 7) << 2;
    ushort4 o;
    o.x = f2b(L[kq + 0][n]);
    o.y = f2b(L[kq + 1][n]);
    o.z = f2b(L[kq + 2][n]);
    o.w = f2b(L[kq + 3][n]);
    *(ushort4*)&dst[(size_t)(n0 + n) * K + k0 + kq] = o;
}

// ---------------- bf16 MFMA GEMM: C[M][N] = A[M][K] @ Wt[N][K]^T ----------------
// Per-dispatch configs (measured; each probed to its local optimum):
//  N=512 GEMMs: 32x32 (4/CU, r17). QKV/CKV: 32x64 (6/4 per CU, r16).
//  FFN1: 64x64 (4/CU, r18). Vocab: 64x128 BK=32 DB=1 (50% occ, r23)
//   + XCD swizzle + fused LSE partials.
// Vocab inner-loop plateau (r12/r23/r25): tile shape, blocks/CU, and prefetch
//  depth all land at 187-200us -> limiter is the per-K-iter sync structure.
// Per-layer wconv kept (r21/r24: L2 locality-in-time beats traffic math).
// Rule #21: swizzle on per-lane GLOBAL source, LDS written linearly.
template<int BM, int BN, int BK, int DB, int RELU, int OUTBF, int LSE, int SWZ>
__global__ __launch_bounds__(256)
void k_mm(const u16* __restrict__ A, const u16* __restrict__ Wt,
          const float* __restrict__ bias, const float* resid,
          void* Cout, int M, int N, int K, int ldc,
          float* __restrict__ pmax, float* __restrict__ psum)
{
    constexpr int MR = BM / 32;      // frag rows per wave
    constexpr int NR = BN / 32;      // frag cols per wave
    constexpr int RPL = (BK == 64) ? 8 : 16;        // rows per gload_lds (1KB)
    constexpr int AIW = BM / (4 * RPL) ? BM / (4 * RPL) : 1;  // gloads per wave (A)
    constexpr int BIW = BN / (4 * RPL) ? BN / (4 * RPL) : 1;
    constexpr int NLD = AIW + BIW;
    constexpr int RS  = BK;                          // row stride in shorts
    __shared__ __align__(16) u16 As[(DB ? 2 : 1) * BM * BK];
    __shared__ __align__(16) u16 Bs[(DB ? 2 : 1) * BN * BK];
    __shared__ float Rm[LSE ? BM * 2 : 1];
    __shared__ float Rs[LSE ? BM * 2 : 1];

    const int tid  = threadIdx.x;
    const int lane = tid & 63;
    const int w    = tid >> 6;

    int bm, bn, bnIdx;
    if (SWZ) {
        int q = gridDim.x >> 3;
        int logical = (blockIdx.x & 7) * q + (blockIdx.x >> 3);
        int mtiles = M / BM;
        bnIdx = logical / mtiles;
        bm = (logical % mtiles) * BM;
        bn = bnIdx * BN;
    } else {
        bn = blockIdx.x * BN; bm = blockIdx.y * BM; bnIdx = blockIdx.x;
    }
    const int wm = (w >> 1) * (MR * 16), wn = (w & 1) * (NR * 16);
    const int fr = lane & 15, fs = lane >> 4;

    // staging geometry (per-lane global pre-swizzle, wave-uniform LDS base)
    const int lrow = lane / (BK / 8);                // BK=64: lane>>3, BK=32: lane>>2
    const int lchk = lane & (BK / 8 - 1);            // chunk within row
    constexpr int SWM = BK / 8 - 1;                  // swizzle mask: 7 or 3
    const u16* aSrc[4]; const u16* bSrc[4];
    int aOff[4], bOff[4];
    #pragma unroll
    for (int j = 0; j < AIW; j++) {
        int row = w * (BM / 4) + j * RPL + lrow;
        aSrc[j] = A + (size_t)(bm + row) * K + ((lchk ^ (row & SWM)) << 3);
        aOff[j] = (w * (BM / 4) + j * RPL) * RS;
    }
    #pragma unroll
    for (int j = 0; j < BIW; j++) {
        int row = w * (BN / 4) + j * RPL + lrow;
        bSrc[j] = Wt + (size_t)(bn + row) * K + ((lchk ^ (row & SWM)) << 3);
        bOff[j] = (w * (BN / 4) + j * RPL) * RS;
    }

    f32x4 acc[MR][NR];
    #pragma unroll
    for (int i = 0; i < MR; i++)
        #pragma unroll
        for (int j = 0; j < NR; j++)
            acc[i][j] = (f32x4){0.f, 0.f, 0.f, 0.f};

    auto compute_tile = [&](const u16* Ab, const u16* Bb) {
        #pragma unroll
        for (int kk = 0; kk < BK / 32; kk++) {
            short8 av[MR], bv[NR];
            #pragma unroll
            for (int i = 0; i < MR; i++) {
                int r = wm + (i << 4) + fr;
                int slot = (((kk << 2) | fs) ^ (r & SWM));
                av[i] = *(const short8*)&Ab[r * RS + (slot << 3)];
            }
            #pragma unroll
            for (int i = 0; i < NR; i++) {
                int r = wn + (i << 4) + fr;
                int slot = (((kk << 2) | fs) ^ (r & SWM));
                bv[i] = *(const short8*)&Bb[r * RS + (slot << 3)];
            }
            #pragma unroll
            for (int mi = 0; mi < MR; mi++)
                #pragma unroll
                for (int ni = 0; ni < NR; ni++)
                    acc[mi][ni] = __builtin_amdgcn_mfma_f32_16x16x32_bf16(
                        av[mi], bv[ni], acc[mi][ni], 0, 0, 0);
        }
    };

    if (DB) {
        // double-buffer, prefetch, counted vmcnt, raw barriers
        #pragma unroll
        for (int j = 0; j < AIW; j++)
            __builtin_amdgcn_global_load_lds((const u16*)aSrc[j], (u16*)&As[aOff[j]], 16, 0, 0);
        #pragma unroll
        for (int j = 0; j < BIW; j++)
            __builtin_amdgcn_global_load_lds((const u16*)bSrc[j], (u16*)&Bs[bOff[j]], 16, 0, 0);
        const int nt = K / BK;
        for (int t = 0; t < nt; t++) {
            const int cur = t & 1;
            if (t + 1 < nt) {
                const int k1 = (t + 1) * BK;
                #pragma unroll
                for (int j = 0; j < AIW; j++)
                    __builtin_amdgcn_global_load_lds((const u16*)(aSrc[j] + k1),
                        (u16*)&As[(cur ^ 1) * BM * BK + aOff[j]], 16, 0, 0);
                #pragma unroll
                for (int j = 0; j < BIW; j++)
                    __builtin_amdgcn_global_load_lds((const u16*)(bSrc[j] + k1),
                        (u16*)&Bs[(cur ^ 1) * BN * BK + bOff[j]], 16, 0, 0);
                vm_wait<NLD>();
            } else {
                vm_wait<0>();
            }
            __builtin_amdgcn_s_barrier();
            __builtin_amdgcn_sched_barrier(0);
            compute_tile(&As[cur * BM * BK], &Bs[cur * BN * BK]);
            __builtin_amdgcn_s_barrier();
        }
    } else {
        // single buffer path
        const int nt = K / BK;
        for (int t = 0; t < nt; t++) {
            const int k0 = t * BK;
            __syncthreads();   // prev tile's reads done before overwrite
            #pragma unroll
            for (int j = 0; j < AIW; j++)
                __builtin_amdgcn_global_load_lds((const u16*)(aSrc[j] + k0),
                                                 (u16*)&As[aOff[j]], 16, 0, 0);
            #pragma unroll
            for (int j = 0; j < BIW; j++)
                __builtin_amdgcn_global_load_lds((const u16*)(bSrc[j] + k0),
                                                 (u16*)&Bs[bOff[j]], 16, 0, 0);
            __syncthreads();   // drain -> tile resident
            compute_tile(As, Bs);
        }
    }

    // epilogue: C row = bm+wm+mi*16+fs*4+i, col = bn+wn+ni*16+fr
    #pragma unroll
    for (int mi = 0; mi < MR; mi++) {
        #pragma unroll
        for (int i = 0; i < 4; i++) {
            int lrow2 = wm + (mi << 4) + (fs << 2) + i;
            int row = bm + lrow2;
            float vv[NR];
            #pragma unroll
            for (int ni = 0; ni < NR; ni++) {
                int ncol = bn + wn + (ni << 4) + fr;
                float v = acc[mi][ni][i];
                if (bias)  v += bias[ncol];
                if (resid) v += resid[(size_t)row * ldc + ncol];
                if (RELU)  v = fmaxf(v, 0.0f);
                vv[ni] = v;
                if (OUTBF) ((u16*)Cout)[(size_t)row * ldc + ncol] = f2b(v);
                else       ((float*)Cout)[(size_t)row * ldc + ncol] = v;
            }
            if (LSE) {
                float mx = vv[0];
                #pragma unroll
                for (int ni = 1; ni < NR; ni++) mx = fmaxf(mx, vv[ni]);
                mx = fmaxf(mx, __shfl_xor(mx, 1));
                mx = fmaxf(mx, __shfl_xor(mx, 2));
                mx = fmaxf(mx, __shfl_xor(mx, 4));
                mx = fmaxf(mx, __shfl_xor(mx, 8));
                float ss = 0.f;
                #pragma unroll
                for (int ni = 0; ni < NR; ni++) ss += __expf(vv[ni] - mx);
                ss += __shfl_xor(ss, 1);
                ss += __shfl_xor(ss, 2);
                ss += __shfl_xor(ss, 4);
                ss += __shfl_xor(ss, 8);
                if (fr == 0) {
                    Rm[lrow2 * 2 + (wn >> 6)] = mx;
                    Rs[lrow2 * 2 + (wn >> 6)] = ss;
                }
            }
        }
    }
    if (LSE) {
        __syncthreads();
        int nbn = N / BN;
        for (int r = tid; r < BM; r += 256) {
            float m0 = Rm[r * 2], m1 = Rm[r * 2 + 1];
            float s0 = Rs[r * 2], s1 = Rs[r * 2 + 1];
            float Mx = fmaxf(m0, m1);
            float Sx = s0 * __expf(m0 - Mx) + s1 * __expf(m1 - Mx);
            pmax[(size_t)(bm + r) * nbn + bnIdx] = Mx;
            psum[(size_t)(bm + r) * nbn + bnIdx] = Sx;
        }
    }
}

// ---------------- lse finalize: reduce partials + subtract in place ----------------
// In-place RMW on d_out is deliberate (r24 lesson): GEMM-written lines are
// L2/HBM-local; the two-stream bf16 variant ran at 2 TB/s and lost 50us.
__global__ __launch_bounds__(256)
void k_lsefin(const float* __restrict__ pmax, const float* __restrict__ psum,
              float* __restrict__ out, int nb)
{
    __shared__ float red[8];
    __shared__ float lsh;
    int row = blockIdx.x;
    int tid = threadIdx.x;
    int lane = tid & 63, wv = tid >> 6;

    float m = -1e30f, s = 0.f;
    if (tid < nb) {
        m = pmax[(size_t)row * nb + tid];
        s = psum[(size_t)row * nb + tid];
    }
    float gm = m;
    #pragma unroll
    for (int off = 32; off; off >>= 1) gm = fmaxf(gm, __shfl_xor(gm, off));
    if (lane == 0) red[wv] = gm;
    __syncthreads();
    gm = fmaxf(fmaxf(red[0], red[1]), fmaxf(red[2], red[3]));

    float c = (tid < nb) ? s * __expf(m - gm) : 0.f;
    #pragma unroll
    for (int off = 32; off; off >>= 1) c += __shfl_xor(c, off);
    if (lane == 0) red[4 + wv] = c;
    __syncthreads();
    if (tid == 0) lsh = gm + logf(red[4] + red[5] + red[6] + red[7]);
    __syncthreads();
    float l = lsh;

    float4* x = (float4*)(out + (size_t)row * VOC_);
    for (int i = tid; i < VOC_ / 4; i += 256) {
        float4 v = x[i];
        v.x -= l; v.y -= l; v.z -= l; v.w -= l;
        x[i] = v;
    }
}

// ---------------- fused flash attention (r18 measured-best QBLK=64 form) ----------------
__global__ __launch_bounds__(256)
void k_fattn(const u16* __restrict__ qkv, int ldq, u16* __restrict__ ctx,
             const int* __restrict__ lengths, int causal)
{
    __shared__ __align__(16) u16 Kls[64 * 64];
    __shared__ __align__(16) u16 Vls[64 * 64];   // V^T: row=d, col=kpos (swizzled)
    __shared__ __align__(16) u16 Pls[4][16 * 64];

    const int bh = blockIdx.y;
    const int b = bh >> 3, hd = bh & 7;
    const int q0 = blockIdx.x << 6;
    const int tid = threadIdx.x;
    const int lane = tid & 63;
    const int w = tid >> 6;
    const int fr = lane & 15, fs = lane >> 4;
    const int g7 = fr & 7;

    const u16* Qp = qkv + (size_t)(b * SEQ + q0 + (w << 4) + fr) * ldq + hd * 64;
    short8 aq[2];
    aq[0] = *(const short8*)(Qp + fs * 8);
    aq[1] = *(const short8*)(Qp + 32 + fs * 8);

    const int len = lengths[b];
    const int ntiles = causal ? (q0 >> 6) + 1 : ((len + 63) >> 6);

    float m[4], l[4];
    f32x4 o[4];
    #pragma unroll
    for (int i = 0; i < 4; i++) { m[i] = -1e30f; l[i] = 0.f; }
    #pragma unroll
    for (int n = 0; n < 4; n++) o[n] = (f32x4){0.f, 0.f, 0.f, 0.f};

    const int srow = tid >> 2;
    const int sc2 = (tid & 3) << 1;
    const u16* Kbase = qkv + 512  + (size_t)(b * SEQ) * ldq + hd * 64;
    const u16* Vbase = qkv + 1024 + (size_t)(b * SEQ) * ldq + hd * 64;

    // prologue: stage tile 0's K/V into named registers
    int4 kA, kB, vA, vB;
    {
        const u16* kr = Kbase + (size_t)srow * ldq;
        kA = *(const int4*)(kr + (sc2 << 3));
        kB = *(const int4*)(kr + (sc2 << 3) + 8);
        const u16* vr = Vbase + (size_t)srow * ldq;
        vA = *(const int4*)(vr + (sc2 << 3));
        vB = *(const int4*)(vr + (sc2 << 3) + 8);
    }

    for (int t = 0; t < ntiles; t++) {
        __syncthreads();   // prev iter's Kls/Vls/Pls consumers done
        {
            *(int4*)&Kls[(srow << 6) + ((sc2 ^ (srow & 7)) << 3)]       = kA;
            *(int4*)&Kls[(srow << 6) + (((sc2 + 1) ^ (srow & 7)) << 3)] = kB;
            int d0 = sc2 << 3;
#define VPUT(j, val) Vls[((d0 + (j)) << 6) + (((srow >> 3) ^ ((j) & 7)) << 3) + (srow & 7)] = (u16)(val)
            VPUT(0,  (unsigned)vA.x); VPUT(1,  ((unsigned)vA.x) >> 16);
            VPUT(2,  (unsigned)vA.y); VPUT(3,  ((unsigned)vA.y) >> 16);
            VPUT(4,  (unsigned)vA.z); VPUT(5,  ((unsigned)vA.z) >> 16);
            VPUT(6,  (unsigned)vA.w); VPUT(7,  ((unsigned)vA.w) >> 16);
            VPUT(8,  (unsigned)vB.x); VPUT(9,  ((unsigned)vB.x) >> 16);
            VPUT(10, (unsigned)vB.y); VPUT(11, ((unsigned)vB.y) >> 16);
            VPUT(12, (unsigned)vB.z); VPUT(13, ((unsigned)vB.z) >> 16);
            VPUT(14, (unsigned)vB.w); VPUT(15, ((unsigned)vB.w) >> 16);
#undef VPUT
        }
        __syncthreads();

        // T14: issue tile t+1's loads NOW; latency hides under QK/softmax/PV
        if (t + 1 < ntiles) {
            const u16* kr = Kbase + (size_t)(((t + 1) << 6) + srow) * ldq;
            kA = *(const int4*)(kr + (sc2 << 3));
            kB = *(const int4*)(kr + (sc2 << 3) + 8);
            const u16* vr = Vbase + (size_t)(((t + 1) << 6) + srow) * ldq;
            vA = *(const int4*)(vr + (sc2 << 3));
            vB = *(const int4*)(vr + (sc2 << 3) + 8);
        }

        f32x4 sf[4];
        #pragma unroll
        for (int n = 0; n < 4; n++) {
            int kr = (n << 4) + fr;
            short8 k0f = *(const short8*)&Kls[(kr << 6) + ((fs ^ g7) << 3)];
            short8 k1f = *(const short8*)&Kls[(kr << 6) + (((4 | fs) ^ g7) << 3)];
            f32x4 z = (f32x4){0.f, 0.f, 0.f, 0.f};
            z = __builtin_amdgcn_mfma_f32_16x16x32_bf16(aq[0], k0f, z, 0, 0, 0);
            z = __builtin_amdgcn_mfma_f32_16x16x32_bf16(aq[1], k1f, z, 0, 0, 0);
            sf[n] = z;
        }
        float tm[4];
        #pragma unroll
        for (int i = 0; i < 4; i++) tm[i] = -1e30f;
        #pragma unroll
        for (int n = 0; n < 4; n++) {
            int kp = (t << 6) + (n << 4) + fr;
            #pragma unroll
            for (int i = 0; i < 4; i++) {
                int qr = q0 + (w << 4) + (fs << 2) + i;
                float v = sf[n][i] * 0.125f;
                bool msk = causal ? (kp > qr) : (kp >= len);
                v = msk ? -1e30f : v;
                sf[n][i] = v;
                tm[i] = fmaxf(tm[i], v);
            }
        }
        #pragma unroll
        for (int i = 0; i < 4; i++) {
            tm[i] = fmaxf(tm[i], __shfl_xor(tm[i], 1));
            tm[i] = fmaxf(tm[i], __shfl_xor(tm[i], 2));
            tm[i] = fmaxf(tm[i], __shfl_xor(tm[i], 4));
            tm[i] = fmaxf(tm[i], __shfl_xor(tm[i], 8));
        }
        float ts[4];
        #pragma unroll
        for (int i = 0; i < 4; i++) {
            float mn = fmaxf(m[i], tm[i]);
            float sc = __expf(m[i] - mn);
            m[i] = mn;
            l[i] *= sc;
            #pragma unroll
            for (int n = 0; n < 4; n++) o[n][i] *= sc;
            ts[i] = 0.f;
        }
        #pragma unroll
        for (int n = 0; n < 4; n++) {
            #pragma unroll
            for (int i = 0; i < 4; i++) {
                float pv = __expf(sf[n][i] - m[i]);
                ts[i] += pv;
                int row = (fs << 2) + i;
                int col = (n << 4) + fr;
                Pls[w][(row << 6) + (((col >> 3) ^ (row & 7)) << 3) + (col & 7)] = f2b(pv);
            }
        }
        #pragma unroll
        for (int i = 0; i < 4; i++) {
            ts[i] += __shfl_xor(ts[i], 1);
            ts[i] += __shfl_xor(ts[i], 2);
            ts[i] += __shfl_xor(ts[i], 4);
            ts[i] += __shfl_xor(ts[i], 8);
            l[i] += ts[i];
        }
        __syncthreads();

        #pragma unroll
        for (int kk = 0; kk < 2; kk++) {
            short8 ap = *(const short8*)&Pls[w][(fr << 6) + ((((kk << 2) | fs) ^ g7) << 3)];
            #pragma unroll
            for (int n = 0; n < 4; n++) {
                int dr = (n << 4) + fr;
                short8 vf = *(const short8*)&Vls[(dr << 6) + ((((kk << 2) | fs) ^ g7) << 3)];
                o[n] = __builtin_amdgcn_mfma_f32_16x16x32_bf16(ap, vf, o[n], 0, 0, 0);
            }
        }
    }

    float inv[4];
    #pragma unroll
    for (int i = 0; i < 4; i++) inv[i] = 1.0f / l[i];
    #pragma unroll
    for (int i = 0; i < 4; i++) {
        size_t base = (size_t)(b * SEQ + q0 + (w << 4) + (fs << 2) + i) * HS_ + hd * 64;
        #pragma unroll
        for (int n = 0; n < 4; n++)
            ctx[base + (n << 4) + fr] = f2b(o[n][i] * inv[i]);
    }
}

} // namespace

extern "C" void kernel_launch(void* const* d_in, const int* in_sizes, int n_in,
                              void* d_out, int out_size, void* d_ws, size_t ws_size,
                              hipStream_t stream)
{
    (void)in_sizes; (void)n_in; (void)out_size; (void)ws_size;
    const int*   x_tokens = (const int*)d_in[0];
    const int*   lengths  = (const int*)d_in[1];
    const int*   y_tokens = (const int*)d_in[2];
    const float* emb_enc  = (const float*)d_in[3];
    const float* emb_dec  = (const float*)d_in[4];
    const float* eWq  = (const float*)d_in[5];
    const float* eWk  = (const float*)d_in[6];
    const float* eWv  = (const float*)d_in[7];
    const float* eWo  = (const float*)d_in[8];
    const float* eln1g = (const float*)d_in[9];
    const float* eln1b = (const float*)d_in[10];
    const float* eln2g = (const float*)d_in[11];
    const float* eln2b = (const float*)d_in[12];
    const float* eW1  = (const float*)d_in[13];
    const float* eb1  = (const float*)d_in[14];
    const float* eW2  = (const float*)d_in[15];
    const float* eb2  = (const float*)d_in[16];
    const float* dsWq = (const float*)d_in[17];
    const float* dsWk = (const float*)d_in[18];
    const float* dsWv = (const float*)d_in[19];
    const float* dsWo = (const float*)d_in[20];
    const float* dcWq = (const float*)d_in[21];
    const float* dcWk = (const float*)d_in[22];
    const float* dcWv = (const float*)d_in[23];
    const float* dcWo = (const float*)d_in[24];
    const float* dln1g = (const float*)d_in[25];
    const float* dln1b = (const float*)d_in[26];
    const float* dln2g = (const float*)d_in[27];
    const float* dln2b = (const float*)d_in[28];
    const float* dln3g = (const float*)d_in[29];
    const float* dln3b = (const float*)d_in[30];
    const float* dW1  = (const float*)d_in[31];
    const float* db1  = (const float*)d_in[32];
    const float* dW2  = (const float*)d_in[33];
    const float* db2  = (const float*)d_in[34];
    const float* glng = (const float*)d_in[35];
    const float* glnb = (const float*)d_in[36];
    const float* gW   = (const float*)d_in[37];
    const float* gb   = (const float*)d_in[38];

    const size_t MH = (size_t)MT * HS_;              // 1,048,576 floats per state

    float* z    = (float*)d_ws;                      // fp32 encoder state
    float* h    = z + MH;                            // fp32 decoder state
    float* big  = h + MH;                            // vwt (8.192M floats) / ffnb overlay
    u16*  vwt   = (u16*)big;                         // [VOC_][HS_] bf16
    u16*  ffnb  = (u16*)big;                         // [MT][FF_] bf16
    float* pmax = big + (size_t)VOC_ * HS_ / 2;      // [MT][250]
    float* psum = pmax + (size_t)MT * 250;
    u16*  qkvb  = (u16*)(psum + (size_t)MT * 250);   // [MT][1536]
    u16*  hnb   = qkvb + (size_t)MT * 1536;
    u16*  kvb   = hnb + MH;
    u16*  ctxb  = kvb + MH;
    u16*  wtb   = ctxb + MH;                         // 8 MB per-layer weights

    const size_t WHH = (size_t)HS_ * HS_;
    const size_t WHF = (size_t)HS_ * FF_;

    const size_t OF_QKV = 0;
    const size_t OF_WO  = 3 * WHH;
    const size_t OF_CQ  = 4 * WHH;
    const size_t OF_CKV = 5 * WHH;
    const size_t OF_CWO = 7 * WHH;
    const size_t OF_W1  = 8 * WHH;
    const size_t OF_W2  = 8 * WHH + WHF;

// N=512 GEMMs: 32x32 tile (1024 blocks = 4/CU)
#define MMS2(RELU, OUTBF, A, W, BIAS, RES, C, M, N, K, LDC) \
    k_mm<32, 32, 64, 1, RELU, OUTBF, 0, 0><<<dim3((N) / 32, (M) / 32), 256, 0, stream>>>( \
        A, W, BIAS, RES, C, M, N, K, LDC, nullptr, nullptr)
// N>=1024 GEMMs: 32x64 tile
#define MMS(RELU, OUTBF, A, W, BIAS, RES, C, M, N, K, LDC) \
    k_mm<32, 64, 64, 1, RELU, OUTBF, 0, 0><<<dim3((N) / 64, (M) / 32), 256, 0, stream>>>( \
        A, W, BIAS, RES, C, M, N, K, LDC, nullptr, nullptr)
// FFN1: 64x64 tile (1024 blocks = 4/CU)
#define MMF(A, W, BIAS, C, M, N, K, LDC) \
    k_mm<64, 64, 64, 1, 1, 1, 0, 0><<<dim3((N) / 64, (M) / 64), 256, 0, stream>>>( \
        A, W, BIAS, nullptr, C, M, N, K, LDC, nullptr, nullptr)

    auto fattn = [&](const u16* qkv, u16* ctxo, int causal) {
        k_fattn<<<dim3(SEQ / 64, NB * NH_), 256, 0, stream>>>(qkv, 1536, ctxo, lengths, causal);
    };

    auto wconv_enc = [&](int i) {
        WSlots s{};
        const float* srcs[6] = {eWq + i * WHH, eWk + i * WHH, eWv + i * WHH,
                                eWo + i * WHH, eW1 + i * WHF, eW2 + i * WHF};
        size_t dofs[6] = {OF_QKV, OF_QKV + WHH, OF_QKV + 2 * WHH, OF_WO, OF_W1, OF_W2};
        int Ks[6] = {512, 512, 512, 512, 512, 2048};
        int Ns[6] = {512, 512, 512, 512, 2048, 512};
        int tot = 0;
        for (int j = 0; j < 6; j++) {
            s.src[j] = srcs[j]; s.dof[j] = dofs[j];
            s.K[j] = Ks[j]; s.N[j] = Ns[j]; s.ktiles[j] = Ks[j] >> 5;
            s.tstart[j] = tot;
            tot += (Ks[j] >> 5) * (Ns[j] >> 5);
        }
        s.ns = 6;
        k_wtm<<<tot, 256, 0, stream>>>(s, wtb);
    };
    auto wconv_dec = [&](int i) {
        WSlots s{};
        const float* srcs[10] = {dsWq + i * WHH, dsWk + i * WHH, dsWv + i * WHH,
                                 dsWo + i * WHH, dcWq + i * WHH, dcWk + i * WHH,
                                 dcWv + i * WHH, dcWo + i * WHH, dW1 + i * WHF, dW2 + i * WHF};
        size_t dofs[10] = {OF_QKV, OF_QKV + WHH, OF_QKV + 2 * WHH, OF_WO, OF_CQ,
                           OF_CKV, OF_CKV + WHH, OF_CWO, OF_W1, OF_W2};
        int Ks[10] = {512, 512, 512, 512, 512, 512, 512, 512, 512, 2048};
        int Ns[10] = {512, 512, 512, 512, 512, 512, 512, 512, 2048, 512};
        int tot = 0;
        for (int j = 0; j < 10; j++) {
            s.src[j] = srcs[j]; s.dof[j] = dofs[j];
            s.K[j] = Ks[j]; s.N[j] = Ns[j]; s.ktiles[j] = Ks[j] >> 5;
            s.tstart[j] = tot;
            tot += (Ks[j] >> 5) * (Ns[j] >> 5);
        }
        s.ns = 10;
        k_wtm<<<tot, 256, 0, stream>>>(s, wtb);
    };

    // embeddings (enc + dec in one launch)
    k_embed2<<<2 * MT, 256, 0, stream>>>(x_tokens, emb_enc, z, y_tokens, emb_dec, h);

    // ---------------- encoder ----------------
    for (int i = 0; i < NL_; i++) {
        wconv_enc(i);
        k_ln<<<MT / 4, 256, 0, stream>>>(z, eln1g + i * HS_, eln1b + i * HS_, hnb);
        MMS(0, 1, hnb, wtb + OF_QKV, nullptr, nullptr, qkvb, MT, 1536, HS_, 1536);
        fattn(qkvb, ctxb, 0);
        MMS2(0, 0, ctxb, wtb + OF_WO, nullptr, z, z, MT, HS_, HS_, HS_);

        k_ln<<<MT / 4, 256, 0, stream>>>(z, eln2g + i * HS_, eln2b + i * HS_, hnb);
        MMF(hnb, wtb + OF_W1, eb1 + i * FF_, ffnb, MT, FF_, HS_, FF_);
        MMS2(0, 0, ffnb, wtb + OF_W2, eb2 + i * HS_, z, z, MT, HS_, FF_, HS_);
    }

    // ---------------- decoder ----------------
    for (int i = 0; i < NL_; i++) {
        wconv_dec(i);

        // self-attn (causal)
        k_ln<<<MT / 4, 256, 0, stream>>>(h, dln1g + i * HS_, dln1b + i * HS_, hnb);
        MMS(0, 1, hnb, wtb + OF_QKV, nullptr, nullptr, qkvb, MT, 1536, HS_, 1536);
        fattn(qkvb, ctxb, 1);
        MMS2(0, 0, ctxb, wtb + OF_WO, nullptr, h, h, MT, HS_, HS_, HS_);

        // cross-attn (dual LN in one launch: z->kvb and h->hnb, same params)
        k_ln2<<<2 * MT / 4, 256, 0, stream>>>(z, kvb, h, hnb,
                                              dln2g + i * HS_, dln2b + i * HS_);
        MMS2(0, 1, hnb, wtb + OF_CQ, nullptr, nullptr, qkvb, MT, HS_, HS_, 1536);
        MMS(0, 1, kvb, wtb + OF_CKV, nullptr, nullptr, qkvb + 512, MT, 1024, HS_, 1536);
        fattn(qkvb, ctxb, 0);
        MMS2(0, 0, ctxb, wtb + OF_CWO, nullptr, h, h, MT, HS_, HS_, HS_);

        // FFN
        k_ln<<<MT / 4, 256, 0, stream>>>(h, dln3g + i * HS_, dln3b + i * HS_, hnb);
        MMF(hnb, wtb + OF_W1, db1 + i * FF_, ffnb, MT, FF_, HS_, FF_);
        MMS2(0, 0, ffnb, wtb + OF_W2, db2 + i * HS_, h, h, MT, HS_, FF_, HS_);
    }

    // ---------------- generator (GEMM + fused log-softmax partials) ----------------
    k_wt<<<dim3(HS_ / 32, VOC_ / 32), 256, 0, stream>>>(gW, vwt, HS_, VOC_);
    k_ln<<<MT / 4, 256, 0, stream>>>(h, glng, glnb, hnb);
    // vocab: 64x128 BK=32 DB=1 (25KB LDS -> 50% occ; grid 8000, XCD swizzle)
    k_mm<64, 128, 32, 1, 0, 0, 1, 1><<<(MT / 64) * (VOC_ / 128), 256, 0, stream>>>(
        hnb, vwt, gb, nullptr, (float*)d_out, MT, VOC_, HS_, VOC_, pmax, psum);
    k_lsefin<<<MT, 256, 0, stream>>>(pmax, psum, (float*)d_out, VOC_ / 128);
#undef MMS
#undef MMS2
#undef MMF
}